// Round 11
// baseline (230.606 us; speedup 1.0000x reference)
//
#include <hip/hip_runtime.h>
#include <math.h>

#define BB 4
#define NN 2048
#define CC 1024
#define HH 16
#define HD 64
#define HALF 32
#define MM (BB*NN)     // 8192
#define K3 (3*CC)      // 3072
#define NF (HH*HALF)   // 512
#define NT (NN/64)     // 32 k-tiles (attn)

typedef __attribute__((ext_vector_type(8))) short bf16x8;
typedef __attribute__((ext_vector_type(4))) float f32x4;
typedef __attribute__((ext_vector_type(16))) float f32x16;
typedef __attribute__((ext_vector_type(4))) unsigned short u16x4;
typedef __attribute__((ext_vector_type(8))) unsigned short u16x8;
typedef __attribute__((ext_vector_type(4))) unsigned int u32x4;

#if __has_builtin(__builtin_amdgcn_exp2f)
#define EXP2(x) __builtin_amdgcn_exp2f(x)
#else
#define EXP2(x) exp2f(x)
#endif
#define AS1 __attribute__((address_space(1)))
#define AS3 __attribute__((address_space(3)))

__device__ __forceinline__ unsigned short f2bf(float f) {
    unsigned int u = __float_as_uint(f);
    unsigned int r = (u + 0x7FFFu + ((u >> 16) & 1u)) >> 16;
    return (unsigned short)r;
}

// ---------------- kernel 1: normalize t arrays ----------------
__global__ __launch_bounds__(256) void tnorm_kernel(const float* t_x, const float* t_y,
                                                    const float* t_z, float* tnorm) {
    int a = blockIdx.x;
    const float* t = (a == 0) ? t_x : ((a == 1) ? t_y : t_z);
    __shared__ float smn[256], smx[256];
    float mn = 1e30f, mx = -1e30f;
    for (int i = threadIdx.x; i < NN; i += 256) {
        float v = t[i];
        mn = fminf(mn, v);
        mx = fmaxf(mx, v);
    }
    smn[threadIdx.x] = mn; smx[threadIdx.x] = mx;
    __syncthreads();
    for (int s = 128; s > 0; s >>= 1) {
        if (threadIdx.x < s) {
            smn[threadIdx.x] = fminf(smn[threadIdx.x], smn[threadIdx.x + s]);
            smx[threadIdx.x] = fmaxf(smx[threadIdx.x], smx[threadIdx.x + s]);
        }
        __syncthreads();
    }
    float lo = smn[0];
    float sc = 32.0f / (smx[0] - lo + 1e-8f);
    for (int i = threadIdx.x; i < NN; i += 256)
        tnorm[a * NN + i] = (t[i] - lo) * sc;
}

// ---------------- kernel 2: angle -> interleaved {cos,sin} table (float2) ----------------
__global__ __launch_bounds__(512) void angle_kernel(const float* freqs, const float* tnorm,
                                                    float* csT) {
    int n = blockIdx.x;
    int hf = threadIdx.x;  // 0..511
    float ang = tnorm[n] * freqs[hf]
              + tnorm[NN + n] * freqs[NF + hf]
              + tnorm[2 * NN + n] * freqs[2 * NF + hf];
    float2 cs;
    cs.x = cosf(ang);
    cs.y = sinf(ang);
    *(float2*)(csT + 2 * ((size_t)n * NF + hf)) = cs;
}

// ---------------- kernel 3: f32 -> bf16 convert (x8) ----------------
__global__ __launch_bounds__(256) void cvt_kernel(const float* __restrict__ src,
                                                  unsigned short* __restrict__ dst, int n) {
    int i = (blockIdx.x * 256 + threadIdx.x) * 8;
    if (i < n) {
        float4 a = *(const float4*)(src + i);
        float4 b = *(const float4*)(src + i + 4);
        u16x8 o;
        o[0] = f2bf(a.x); o[1] = f2bf(a.y); o[2] = f2bf(a.z); o[3] = f2bf(a.w);
        o[4] = f2bf(b.x); o[5] = f2bf(b.y); o[6] = f2bf(b.z); o[7] = f2bf(b.w);
        *(u16x8*)(dst + i) = o;
    }
}

// ---------------- kernel 4: QKV GEMM (bf16 MFMA) + fused RoPE (verified r7 math) ----------------
// XCD-swizzled 1D grid (1536 = 8 XCD x 192); writes q,k [bh][n][d]; v transposed [bh][d][n]
__global__ __launch_bounds__(256) void qkv_gemm_kernel(const unsigned short* __restrict__ A,
                                                       const unsigned short* __restrict__ Bw,
                                                       const float* __restrict__ csT,
                                                       unsigned short* __restrict__ qb,
                                                       unsigned short* __restrict__ kb,
                                                       unsigned short* __restrict__ vbT) {
    __shared__ unsigned short Asl[128 * 64];
    __shared__ unsigned short Bsl[128 * 64];
    const int tid = threadIdx.x;
    const int wv = tid >> 6, l = tid & 63;
    const int wm = wv >> 1, wn = wv & 1;
    const int lg = l >> 4, l15 = l & 15;
    const int bid = blockIdx.x;                  // 0..1535
    const int wgid = (bid & 7) * 192 + (bid >> 3);   // bijective XCD chunking
    const int m0 = (wgid & 63) * 128;
    const int n0 = (wgid >> 6) * 128;

    f32x4 acc[4][4];
#pragma unroll
    for (int i = 0; i < 4; i++)
#pragma unroll
        for (int j = 0; j < 4; j++) acc[i][j] = f32x4{0.f, 0.f, 0.f, 0.f};

    for (int kt = 0; kt < CC; kt += 64) {
        __syncthreads();
#pragma unroll
        for (int i = 0; i < 4; i++) {
            int c = (wv * 4 + i) * 64 + l;
            int r = c >> 3, kc = c & 7;
            int sc = kt + ((kc ^ (r & 7)) * 8);
            __builtin_amdgcn_global_load_lds(
                (AS1 void*)(A + (size_t)(m0 + r) * CC + sc),
                (AS3 void*)(&Asl[(wv * 4 + i) * 512]), 16, 0, 0);
            __builtin_amdgcn_global_load_lds(
                (AS1 void*)(Bw + (size_t)(n0 + r) * CC + sc),
                (AS3 void*)(&Bsl[(wv * 4 + i) * 512]), 16, 0, 0);
        }
        __syncthreads();
#pragma unroll
        for (int kc = 0; kc < 2; kc++) {
            bf16x8 af[4], bfr[4];
#pragma unroll
            for (int mi = 0; mi < 4; mi++) {
                int r = wm * 64 + mi * 16 + l15;
                af[mi] = *(const bf16x8*)(&Asl[r * 64 + (((kc * 4 + lg) ^ (r & 7)) * 8)]);
            }
#pragma unroll
            for (int nj = 0; nj < 4; nj++) {
                int r = wn * 64 + nj * 16 + l15;
                bfr[nj] = *(const bf16x8*)(&Bsl[r * 64 + (((kc * 4 + lg) ^ (r & 7)) * 8)]);
            }
#pragma unroll
            for (int mi = 0; mi < 4; mi++)
#pragma unroll
                for (int nj = 0; nj < 4; nj++)
                    acc[mi][nj] = __builtin_amdgcn_mfma_f32_16x16x32_bf16(af[mi], bfr[nj], acc[mi][nj], 0, 0, 0);
        }
    }
    // epilogue: RoPE for q/k ([bh][n][d]); v transposed ([bh][d][n])
    const int b_ = m0 >> 11;
    const int nrow0 = (m0 & (NN - 1));
#pragma unroll
    for (int nj = 0; nj < 4; nj++) {
        int oc = n0 + wn * 64 + nj * 16 + l15;
        int s = oc >> 10;
        int rr = oc & 1023;
        int h = rr >> 6;
        int d = rr & 63;
        int f = d >> 1;
#pragma unroll
        for (int mi = 0; mi < 4; mi++) {
            f32x4 v = acc[mi][nj];
            if (s == 2) {
                u16x4 vv;
#pragma unroll
                for (int reg = 0; reg < 4; reg++) vv[reg] = f2bf(v[reg]);
                int nb = nrow0 + wm * 64 + mi * 16 + lg * 4;
                *(u16x4*)(vbT + ((size_t)((b_ * HH + h) * HD + d)) * NN + nb) = vv;
            } else {
#pragma unroll
                for (int reg = 0; reg < 4; reg++) {
                    int m = m0 + wm * 64 + mi * 16 + lg * 4 + reg;
                    int n = m & (NN - 1);
                    float val = v[reg];
                    float partner = __shfl_xor(val, 1);
                    size_t base = (((size_t)(b_ * HH + h)) * NN + n) * HD + d;
                    float2 cs2 = *(const float2*)(csT + 2 * ((size_t)n * NF + h * HALF + f));
                    float res = ((d & 1) == 0) ? (val * cs2.x - partner * cs2.y)
                                               : (val * cs2.x + partner * cs2.y);
                    if (s == 0) res *= 0.18033688011112043f;  // 0.125 * log2(e)
                    (s == 0 ? qb : kb)[base] = f2bf(res);
                }
            }
        }
    }
}

// ---------------- kernel 5: flash attention (verified round-7 version) ----------------
template<int BUF>
__device__ __forceinline__ void attn_iter(
    unsigned short* LB, bool do_stage, int wv, int l31,
    const unsigned short*& kn0, const unsigned short*& kn1,
    const unsigned short*& vn0, const unsigned short*& vn1,
    const int (&so)[4], const bf16x8 (&qfA)[4], const bf16x8 (&qfB)[4],
    const f32x16& Z, const bf16x8& ones,
    f32x16& OA0, f32x16& OA1, f32x16& OB0, f32x16& OB1,
    f32x16& SsA, f32x16& SsB) {
    if (do_stage) {
        const int nb = (BUF ^ 1) * 4096;
        __builtin_amdgcn_global_load_lds((AS1 void*)kn0, (AS3 void*)(&LB[nb + (wv * 2 + 0) * 512]), 16, 0, 0);
        __builtin_amdgcn_global_load_lds((AS1 void*)kn1, (AS3 void*)(&LB[nb + (wv * 2 + 1) * 512]), 16, 0, 0);
        __builtin_amdgcn_global_load_lds((AS1 void*)vn0, (AS3 void*)(&LB[8192 + nb + (wv * 2 + 0) * 512]), 16, 0, 0);
        __builtin_amdgcn_global_load_lds((AS1 void*)vn1, (AS3 void*)(&LB[8192 + nb + (wv * 2 + 1) * 512]), 16, 0, 0);
        kn0 += 4096; kn1 += 4096; vn0 += 64; vn1 += 64;
    }
    f32x16 sA0, sA1, sB0, sB1;
    __builtin_amdgcn_s_setprio(1);
    {
        bf16x8 a0 = *(const bf16x8*)(LB + BUF * 4096 + l31 * 64 + so[0]);
        bf16x8 a1 = *(const bf16x8*)(LB + BUF * 4096 + (32 + l31) * 64 + so[0]);
        sA0 = __builtin_amdgcn_mfma_f32_32x32x16_bf16(a0, qfA[0], Z, 0, 0, 0);
        sA1 = __builtin_amdgcn_mfma_f32_32x32x16_bf16(a1, qfA[0], Z, 0, 0, 0);
        sB0 = __builtin_amdgcn_mfma_f32_32x32x16_bf16(a0, qfB[0], Z, 0, 0, 0);
        sB1 = __builtin_amdgcn_mfma_f32_32x32x16_bf16(a1, qfB[0], Z, 0, 0, 0);
    }
#pragma unroll
    for (int dc = 1; dc < 4; dc++) {
        bf16x8 a0 = *(const bf16x8*)(LB + BUF * 4096 + l31 * 64 + so[dc]);
        bf16x8 a1 = *(const bf16x8*)(LB + BUF * 4096 + (32 + l31) * 64 + so[dc]);
        sA0 = __builtin_amdgcn_mfma_f32_32x32x16_bf16(a0, qfA[dc], sA0, 0, 0, 0);
        sA1 = __builtin_amdgcn_mfma_f32_32x32x16_bf16(a1, qfA[dc], sA1, 0, 0, 0);
        sB0 = __builtin_amdgcn_mfma_f32_32x32x16_bf16(a0, qfB[dc], sB0, 0, 0, 0);
        sB1 = __builtin_amdgcn_mfma_f32_32x32x16_bf16(a1, qfB[dc], sB1, 0, 0, 0);
    }
    __builtin_amdgcn_s_setprio(0);
#pragma unroll
    for (int r = 0; r < 16; r++) {
        sA0[r] = EXP2(sA0[r]); sA1[r] = EXP2(sA1[r]);
        sB0[r] = EXP2(sB0[r]); sB1[r] = EXP2(sB1[r]);
    }
#pragma unroll
    for (int r = 0; r < 8; r++) {
        unsigned u0, u1, u2, u3;
        asm("v_cvt_pk_bf16_f32 %0, %1, %2" : "=v"(u0) : "v"(sA0[2 * r]), "v"(sA0[2 * r + 1]));
        asm("v_cvt_pk_bf16_f32 %0, %1, %2" : "=v"(u1) : "v"(sA1[2 * r]), "v"(sA1[2 * r + 1]));
        asm("v_cvt_pk_bf16_f32 %0, %1, %2" : "=v"(u2) : "v"(sB0[2 * r]), "v"(sB0[2 * r + 1]));
        asm("v_cvt_pk_bf16_f32 %0, %1, %2" : "=v"(u3) : "v"(sB1[2 * r]), "v"(sB1[2 * r + 1]));
        sA0[2 * r] = __uint_as_float(u0);
        sA1[2 * r] = __uint_as_float(u1);
        sB0[2 * r] = __uint_as_float(u2);
        sB1[2 * r] = __uint_as_float(u3);
    }
    __builtin_amdgcn_s_setprio(1);
#pragma unroll
    for (int kc = 0; kc < 4; kc++) {
        const int bs = (kc & 1) * 8;
        bf16x8 pfA, pfB;
        {
            float e0 = (kc < 2) ? sA0[bs + 0] : sA1[bs + 0];
            float e4 = (kc < 2) ? sA0[bs + 4] : sA1[bs + 4];
            float e2 = (kc < 2) ? sA0[bs + 2] : sA1[bs + 2];
            float e6 = (kc < 2) ? sA0[bs + 6] : sA1[bs + 6];
            auto uA = __builtin_amdgcn_permlane32_swap(__float_as_uint(e0), __float_as_uint(e4), false, false);
            auto uB = __builtin_amdgcn_permlane32_swap(__float_as_uint(e2), __float_as_uint(e6), false, false);
            u32x4 t; t.x = uA[0]; t.y = uB[0]; t.z = uA[1]; t.w = uB[1];
            pfA = __builtin_bit_cast(bf16x8, t);
        }
        {
            float e0 = (kc < 2) ? sB0[bs + 0] : sB1[bs + 0];
            float e4 = (kc < 2) ? sB0[bs + 4] : sB1[bs + 4];
            float e2 = (kc < 2) ? sB0[bs + 2] : sB1[bs + 2];
            float e6 = (kc < 2) ? sB0[bs + 6] : sB1[bs + 6];
            auto uA = __builtin_amdgcn_permlane32_swap(__float_as_uint(e0), __float_as_uint(e4), false, false);
            auto uB = __builtin_amdgcn_permlane32_swap(__float_as_uint(e2), __float_as_uint(e6), false, false);
            u32x4 t; t.x = uA[0]; t.y = uB[0]; t.z = uA[1]; t.w = uB[1];
            pfB = __builtin_bit_cast(bf16x8, t);
        }
        bf16x8 va  = *(const bf16x8*)(LB + 8192 + BUF * 4096 + l31 * 64 + so[kc]);
        bf16x8 vb2 = *(const bf16x8*)(LB + 8192 + BUF * 4096 + (32 + l31) * 64 + so[kc]);
        OA0 = __builtin_amdgcn_mfma_f32_32x32x16_bf16(va,  pfA, OA0, 0, 0, 0);
        OA1 = __builtin_amdgcn_mfma_f32_32x32x16_bf16(vb2, pfA, OA1, 0, 0, 0);
        OB0 = __builtin_amdgcn_mfma_f32_32x32x16_bf16(va,  pfB, OB0, 0, 0, 0);
        OB1 = __builtin_amdgcn_mfma_f32_32x32x16_bf16(vb2, pfB, OB1, 0, 0, 0);
        SsA = __builtin_amdgcn_mfma_f32_32x32x16_bf16(ones, pfA, SsA, 0, 0, 0);
        SsB = __builtin_amdgcn_mfma_f32_32x32x16_bf16(ones, pfB, SsB, 0, 0, 0);
    }
    __builtin_amdgcn_s_setprio(0);
    __syncthreads();
}

__global__ __launch_bounds__(256, 2) void attn_mfma_kernel(const unsigned short* __restrict__ qbp,
                                                           const unsigned short* __restrict__ kbp,
                                                           const unsigned short* __restrict__ vtp,
                                                           unsigned short* __restrict__ aout) {
    __shared__ unsigned short LB[4 * 4096];      // K0,K1,V0,V1
    const int tid = threadIdx.x;
    const int wv = tid >> 6;       // 0..3
    const int l = tid & 63;
    const int l31 = l & 31, hi = l >> 5;

    const int wg = blockIdx.x;                    // 0..511
    const int Lidx = (wg & 7) * 64 + (wg >> 3);
    const int bh = Lidx >> 3;
    const int q0 = (Lidx & 7) * 256;

    const unsigned short* qp = qbp + (size_t)bh * (NN * HD);
    const unsigned short* kp = kbp + (size_t)bh * (NN * HD);
    const unsigned short* vp = vtp + (size_t)bh * (NN * HD);

    const int r0 = (wv * 2 + 0) * 8 + (l >> 3);
    const int r1 = (wv * 2 + 1) * 8 + (l >> 3);
    const int c0 = ((l & 7) ^ (r0 & 7)) * 8;
    const int c1 = ((l & 7) ^ (r1 & 7)) * 8;
    const unsigned short* kn0 = kp + r0 * HD + c0;
    const unsigned short* kn1 = kp + r1 * HD + c1;
    const unsigned short* vn0 = vp + (size_t)r0 * NN + c0;
    const unsigned short* vn1 = vp + (size_t)r1 * NN + c1;

    __builtin_amdgcn_global_load_lds((AS1 void*)kn0, (AS3 void*)(&LB[(wv * 2 + 0) * 512]), 16, 0, 0);
    __builtin_amdgcn_global_load_lds((AS1 void*)kn1, (AS3 void*)(&LB[(wv * 2 + 1) * 512]), 16, 0, 0);
    __builtin_amdgcn_global_load_lds((AS1 void*)vn0, (AS3 void*)(&LB[8192 + (wv * 2 + 0) * 512]), 16, 0, 0);
    __builtin_amdgcn_global_load_lds((AS1 void*)vn1, (AS3 void*)(&LB[8192 + (wv * 2 + 1) * 512]), 16, 0, 0);
    kn0 += 4096; kn1 += 4096; vn0 += 64; vn1 += 64;

    const unsigned short* qr = qp + (size_t)(q0 + wv * 64 + l31) * HD;
    bf16x8 qfA[4], qfB[4];
#pragma unroll
    for (int dc = 0; dc < 4; dc++) {
        qfA[dc] = *(const bf16x8*)(qr + dc * 16 + hi * 8);
        qfB[dc] = *(const bf16x8*)(qr + 32 * HD + dc * 16 + hi * 8);
    }

    int so[4];
#pragma unroll
    for (int i = 0; i < 4; i++) so[i] = ((2 * i + hi) ^ (l31 & 7)) * 8;

    f32x16 Z;
#pragma unroll
    for (int r = 0; r < 16; r++) Z[r] = 0.0f;
    f32x16 OA0 = Z, OA1 = Z, OB0 = Z, OB1 = Z, SsA = Z, SsB = Z;
    bf16x8 ones;
#pragma unroll
    for (int j = 0; j < 8; j++) ones[j] = (short)0x3F80;  // bf16 1.0

    __syncthreads();

    for (int ktb = 0; ktb < NT; ktb += 2) {
        attn_iter<0>(LB, true, wv, l31, kn0, kn1, vn0, vn1, so, qfA, qfB,
                     Z, ones, OA0, OA1, OB0, OB1, SsA, SsB);
        attn_iter<1>(LB, ktb + 2 < NT, wv, l31, kn0, kn1, vn0, vn1, so, qfA, qfB,
                     Z, ones, OA0, OA1, OB0, OB1, SsA, SsB);
    }

    const int b_ = bh >> 4, hh = bh & 15;
    const float invA = 1.0f / SsA[0], invB = 1.0f / SsB[0];
    const size_t mrowA = (size_t)(b_ * NN + q0 + wv * 64 + l31) * CC + hh * HD;
    const size_t mrowB = mrowA + (size_t)32 * CC;
#pragma unroll
    for (int rq = 0; rq < 4; rq++) {
        u16x4 a0, a1, b0, b1;
#pragma unroll
        for (int j = 0; j < 4; j++) {
            a0[j] = f2bf(OA0[rq * 4 + j] * invA);
            a1[j] = f2bf(OA1[rq * 4 + j] * invA);
            b0[j] = f2bf(OB0[rq * 4 + j] * invB);
            b1[j] = f2bf(OB1[rq * 4 + j] * invB);
        }
        *(u16x4*)(aout + mrowA + rq * 8 + hi * 4) = a0;
        *(u16x4*)(aout + mrowA + 32 + rq * 8 + hi * 4) = a1;
        *(u16x4*)(aout + mrowB + rq * 8 + hi * 4) = b0;
        *(u16x4*)(aout + mrowB + 32 + rq * 8 + hi * 4) = b1;
    }
}

// ---------------- kernel 6: proj GEMM (bf16 MFMA) + bias, XCD-swizzled ----------------
__global__ __launch_bounds__(256) void proj_gemm_kernel(const unsigned short* __restrict__ A,
                                                        const unsigned short* __restrict__ Bw,
                                                        const float* __restrict__ bp,
                                                        float* __restrict__ out) {
    __shared__ unsigned short Asl[128 * 64];
    __shared__ unsigned short Bsl[128 * 64];
    const int tid = threadIdx.x;
    const int wv = tid >> 6, l = tid & 63;
    const int wm = wv >> 1, wn = wv & 1;
    const int lg = l >> 4, l15 = l & 15;
    const int bid = blockIdx.x;                  // 0..511
    const int wgid = (bid & 7) * 64 + (bid >> 3);    // bijective XCD chunking
    const int m0 = (wgid & 63) * 128;
    const int n0 = (wgid >> 6) * 128;

    f32x4 acc[4][4];
#pragma unroll
    for (int i = 0; i < 4; i++)
#pragma unroll
        for (int j = 0; j < 4; j++) acc[i][j] = f32x4{0.f, 0.f, 0.f, 0.f};

    for (int kt = 0; kt < CC; kt += 64) {
        __syncthreads();
#pragma unroll
        for (int i = 0; i < 4; i++) {
            int c = (wv * 4 + i) * 64 + l;
            int r = c >> 3, kc = c & 7;
            int sc = kt + ((kc ^ (r & 7)) * 8);
            __builtin_amdgcn_global_load_lds(
                (AS1 void*)(A + (size_t)(m0 + r) * CC + sc),
                (AS3 void*)(&Asl[(wv * 4 + i) * 512]), 16, 0, 0);
            __builtin_amdgcn_global_load_lds(
                (AS1 void*)(Bw + (size_t)(n0 + r) * CC + sc),
                (AS3 void*)(&Bsl[(wv * 4 + i) * 512]), 16, 0, 0);
        }
        __syncthreads();
#pragma unroll
        for (int kc = 0; kc < 2; kc++) {
            bf16x8 af[4], bfr[4];
#pragma unroll
            for (int mi = 0; mi < 4; mi++) {
                int r = wm * 64 + mi * 16 + l15;
                af[mi] = *(const bf16x8*)(&Asl[r * 64 + (((kc * 4 + lg) ^ (r & 7)) * 8)]);
            }
#pragma unroll
            for (int nj = 0; nj < 4; nj++) {
                int r = wn * 64 + nj * 16 + l15;
                bfr[nj] = *(const bf16x8*)(&Bsl[r * 64 + (((kc * 4 + lg) ^ (r & 7)) * 8)]);
            }
#pragma unroll
            for (int mi = 0; mi < 4; mi++)
#pragma unroll
                for (int nj = 0; nj < 4; nj++)
                    acc[mi][nj] = __builtin_amdgcn_mfma_f32_16x16x32_bf16(af[mi], bfr[nj], acc[mi][nj], 0, 0, 0);
        }
    }
    float bias[4];
#pragma unroll
    for (int nj = 0; nj < 4; nj++) bias[nj] = bp[n0 + wn * 64 + nj * 16 + l15];
#pragma unroll
    for (int mi = 0; mi < 4; mi++)
#pragma unroll
        for (int nj = 0; nj < 4; nj++) {
            int oc = n0 + wn * 64 + nj * 16 + l15;
#pragma unroll
            for (int reg = 0; reg < 4; reg++) {
                int m = m0 + wm * 64 + mi * 16 + lg * 4 + reg;
                out[(size_t)m * CC + oc] = acc[mi][nj][reg] + bias[nj];
            }
        }
}

extern "C" void kernel_launch(void* const* d_in, const int* in_sizes, int n_in,
                              void* d_out, int out_size, void* d_ws, size_t ws_size,
                              hipStream_t stream) {
    const float* x      = (const float*)d_in[0];
    const float* t_x    = (const float*)d_in[1];
    const float* t_y    = (const float*)d_in[2];
    const float* t_z    = (const float*)d_in[3];
    const float* w_qkv  = (const float*)d_in[4];
    const float* w_proj = (const float*)d_in[5];
    const float* b_proj = (const float*)d_in[6];
    const float* freqs  = (const float*)d_in[7];
    float* out = (float*)d_out;

    unsigned short* xb     = (unsigned short*)d_ws;            // MM*CC
    unsigned short* wqkvb  = xb + (size_t)MM * CC;             // K3*CC
    unsigned short* wprojb = wqkvb + (size_t)K3 * CC;          // CC*CC
    unsigned short* qbuf   = wprojb + (size_t)CC * CC;         // B*H*N*HD
    unsigned short* kbuf   = qbuf + (size_t)BB * HH * NN * HD;
    unsigned short* vbT    = kbuf + (size_t)BB * HH * NN * HD; // [bh][d][n]
    unsigned short* attnb  = vbT + (size_t)BB * HH * NN * HD;
    float* csT   = (float*)(attnb + (size_t)MM * CC);          // NN*NF float2
    float* tnorm = csT + (size_t)2 * NN * NF;

    tnorm_kernel<<<3, 256, 0, stream>>>(t_x, t_y, t_z, tnorm);
    angle_kernel<<<NN, 512, 0, stream>>>(freqs, tnorm, csT);
    cvt_kernel<<<(MM * CC) / 2048, 256, 0, stream>>>(x, xb, MM * CC);
    cvt_kernel<<<(K3 * CC) / 2048, 256, 0, stream>>>(w_qkv, wqkvb, K3 * CC);
    cvt_kernel<<<(CC * CC) / 2048, 256, 0, stream>>>(w_proj, wprojb, CC * CC);
    qkv_gemm_kernel<<<1536, 256, 0, stream>>>(xb, wqkvb, csT, qbuf, kbuf, vbT);
    attn_mfma_kernel<<<512, 256, 0, stream>>>(qbuf, kbuf, vbT, attnb);
    proj_gemm_kernel<<<512, 256, 0, stream>>>(attnb, wprojb, b_proj, out);
}

// Round 12
// 222.683 us; speedup vs baseline: 1.0356x; 1.0356x over previous
//
#include <hip/hip_runtime.h>
#include <math.h>

#define BB 4
#define NN 2048
#define CC 1024
#define HH 16
#define HD 64
#define HALF 32
#define MM (BB*NN)     // 8192
#define K3 (3*CC)      // 3072
#define NF (HH*HALF)   // 512
#define NT (NN/64)     // 32 k-tiles (attn)

typedef __attribute__((ext_vector_type(8))) short bf16x8;
typedef __attribute__((ext_vector_type(4))) float f32x4;
typedef __attribute__((ext_vector_type(16))) float f32x16;
typedef __attribute__((ext_vector_type(4))) unsigned short u16x4;
typedef __attribute__((ext_vector_type(8))) unsigned short u16x8;
typedef __attribute__((ext_vector_type(4))) unsigned int u32x4;

#if __has_builtin(__builtin_amdgcn_exp2f)
#define EXP2(x) __builtin_amdgcn_exp2f(x)
#else
#define EXP2(x) exp2f(x)
#endif
#define AS1 __attribute__((address_space(1)))
#define AS3 __attribute__((address_space(3)))

__device__ __forceinline__ unsigned short f2bf(float f) {
    unsigned int u = __float_as_uint(f);
    unsigned int r = (u + 0x7FFFu + ((u >> 16) & 1u)) >> 16;
    return (unsigned short)r;
}

// ---------------- kernel 1: normalize t arrays ----------------
__global__ __launch_bounds__(256) void tnorm_kernel(const float* t_x, const float* t_y,
                                                    const float* t_z, float* tnorm) {
    int a = blockIdx.x;
    const float* t = (a == 0) ? t_x : ((a == 1) ? t_y : t_z);
    __shared__ float smn[256], smx[256];
    float mn = 1e30f, mx = -1e30f;
    for (int i = threadIdx.x; i < NN; i += 256) {
        float v = t[i];
        mn = fminf(mn, v);
        mx = fmaxf(mx, v);
    }
    smn[threadIdx.x] = mn; smx[threadIdx.x] = mx;
    __syncthreads();
    for (int s = 128; s > 0; s >>= 1) {
        if (threadIdx.x < s) {
            smn[threadIdx.x] = fminf(smn[threadIdx.x], smn[threadIdx.x + s]);
            smx[threadIdx.x] = fmaxf(smx[threadIdx.x], smx[threadIdx.x + s]);
        }
        __syncthreads();
    }
    float lo = smn[0];
    float sc = 32.0f / (smx[0] - lo + 1e-8f);
    for (int i = threadIdx.x; i < NN; i += 256)
        tnorm[a * NN + i] = (t[i] - lo) * sc;
}

// ---------------- kernel 2: angle -> interleaved {cos,sin} table (float2) ----------------
__global__ __launch_bounds__(512) void angle_kernel(const float* freqs, const float* tnorm,
                                                    float* csT) {
    int n = blockIdx.x;
    int hf = threadIdx.x;  // 0..511
    float ang = tnorm[n] * freqs[hf]
              + tnorm[NN + n] * freqs[NF + hf]
              + tnorm[2 * NN + n] * freqs[2 * NF + hf];
    float2 cs;
    cs.x = cosf(ang);
    cs.y = sinf(ang);
    *(float2*)(csT + 2 * ((size_t)n * NF + hf)) = cs;
}

// ---------------- kernel 3: f32 -> bf16 convert (x8) ----------------
__global__ __launch_bounds__(256) void cvt_kernel(const float* __restrict__ src,
                                                  unsigned short* __restrict__ dst, int n) {
    int i = (blockIdx.x * 256 + threadIdx.x) * 8;
    if (i < n) {
        float4 a = *(const float4*)(src + i);
        float4 b = *(const float4*)(src + i + 4);
        u16x8 o;
        o[0] = f2bf(a.x); o[1] = f2bf(a.y); o[2] = f2bf(a.z); o[3] = f2bf(a.w);
        o[4] = f2bf(b.x); o[5] = f2bf(b.y); o[6] = f2bf(b.z); o[7] = f2bf(b.w);
        *(u16x8*)(dst + i) = o;
    }
}

// ---------------- kernel 4: QKV GEMM (bf16 MFMA) + fused RoPE (2D grid, verified) ----------------
__global__ __launch_bounds__(256) void qkv_gemm_kernel(const unsigned short* __restrict__ A,
                                                       const unsigned short* __restrict__ Bw,
                                                       const float* __restrict__ csT,
                                                       unsigned short* __restrict__ qb,
                                                       unsigned short* __restrict__ kb,
                                                       unsigned short* __restrict__ vbT) {
    __shared__ unsigned short Asl[128 * 64];
    __shared__ unsigned short Bsl[128 * 64];
    const int tid = threadIdx.x;
    const int wv = tid >> 6, l = tid & 63;
    const int wm = wv >> 1, wn = wv & 1;
    const int lg = l >> 4, l15 = l & 15;
    const int m0 = blockIdx.x * 128, n0 = blockIdx.y * 128;

    f32x4 acc[4][4];
#pragma unroll
    for (int i = 0; i < 4; i++)
#pragma unroll
        for (int j = 0; j < 4; j++) acc[i][j] = f32x4{0.f, 0.f, 0.f, 0.f};

    for (int kt = 0; kt < CC; kt += 64) {
        __syncthreads();
#pragma unroll
        for (int i = 0; i < 4; i++) {
            int c = (wv * 4 + i) * 64 + l;
            int r = c >> 3, kc = c & 7;
            int sc = kt + ((kc ^ (r & 7)) * 8);
            __builtin_amdgcn_global_load_lds(
                (AS1 void*)(A + (size_t)(m0 + r) * CC + sc),
                (AS3 void*)(&Asl[(wv * 4 + i) * 512]), 16, 0, 0);
            __builtin_amdgcn_global_load_lds(
                (AS1 void*)(Bw + (size_t)(n0 + r) * CC + sc),
                (AS3 void*)(&Bsl[(wv * 4 + i) * 512]), 16, 0, 0);
        }
        __syncthreads();
#pragma unroll
        for (int kc = 0; kc < 2; kc++) {
            bf16x8 af[4], bfr[4];
#pragma unroll
            for (int mi = 0; mi < 4; mi++) {
                int r = wm * 64 + mi * 16 + l15;
                af[mi] = *(const bf16x8*)(&Asl[r * 64 + (((kc * 4 + lg) ^ (r & 7)) * 8)]);
            }
#pragma unroll
            for (int nj = 0; nj < 4; nj++) {
                int r = wn * 64 + nj * 16 + l15;
                bfr[nj] = *(const bf16x8*)(&Bsl[r * 64 + (((kc * 4 + lg) ^ (r & 7)) * 8)]);
            }
#pragma unroll
            for (int mi = 0; mi < 4; mi++)
#pragma unroll
                for (int nj = 0; nj < 4; nj++)
                    acc[mi][nj] = __builtin_amdgcn_mfma_f32_16x16x32_bf16(af[mi], bfr[nj], acc[mi][nj], 0, 0, 0);
        }
    }
    // epilogue: RoPE for q/k ([bh][n][d]); v transposed ([bh][d][n])
    const int b_ = m0 >> 11;
    const int nrow0 = (m0 & (NN - 1));
#pragma unroll
    for (int nj = 0; nj < 4; nj++) {
        int oc = n0 + wn * 64 + nj * 16 + l15;
        int s = oc >> 10;
        int rr = oc & 1023;
        int h = rr >> 6;
        int d = rr & 63;
        int f = d >> 1;
#pragma unroll
        for (int mi = 0; mi < 4; mi++) {
            f32x4 v = acc[mi][nj];
            if (s == 2) {
                u16x4 vv;
#pragma unroll
                for (int reg = 0; reg < 4; reg++) vv[reg] = f2bf(v[reg]);
                int nb = nrow0 + wm * 64 + mi * 16 + lg * 4;
                *(u16x4*)(vbT + ((size_t)((b_ * HH + h) * HD + d)) * NN + nb) = vv;
            } else {
#pragma unroll
                for (int reg = 0; reg < 4; reg++) {
                    int m = m0 + wm * 64 + mi * 16 + lg * 4 + reg;
                    int n = m & (NN - 1);
                    float val = v[reg];
                    float partner = __shfl_xor(val, 1);
                    size_t base = (((size_t)(b_ * HH + h)) * NN + n) * HD + d;
                    float2 cs2 = *(const float2*)(csT + 2 * ((size_t)n * NF + h * HALF + f));
                    float res = ((d & 1) == 0) ? (val * cs2.x - partner * cs2.y)
                                               : (val * cs2.x + partner * cs2.y);
                    if (s == 0) res *= 0.18033688011112043f;  // 0.125 * log2(e)
                    (s == 0 ? qb : kb)[base] = f2bf(res);
                }
            }
        }
    }
}

// ---------------- kernel 5: flash attention, QBLK=128, 4 waves x 32 q-rows ----------------
// Same verified iteration code as round-7 minus the second q-set; grid 1024 -> 4 blocks/CU.
template<int BUF>
__device__ __forceinline__ void attn_iter(
    unsigned short* LB, bool do_stage, int wv, int l31,
    const unsigned short*& kn0, const unsigned short*& kn1,
    const unsigned short*& vn0, const unsigned short*& vn1,
    const int (&so)[4], const bf16x8 (&qf)[4],
    const f32x16& Z, const bf16x8& ones,
    f32x16& O0, f32x16& O1, f32x16& Ss) {
    if (do_stage) {
        const int nb = (BUF ^ 1) * 4096;
        __builtin_amdgcn_global_load_lds((AS1 void*)kn0, (AS3 void*)(&LB[nb + (wv * 2 + 0) * 512]), 16, 0, 0);
        __builtin_amdgcn_global_load_lds((AS1 void*)kn1, (AS3 void*)(&LB[nb + (wv * 2 + 1) * 512]), 16, 0, 0);
        __builtin_amdgcn_global_load_lds((AS1 void*)vn0, (AS3 void*)(&LB[8192 + nb + (wv * 2 + 0) * 512]), 16, 0, 0);
        __builtin_amdgcn_global_load_lds((AS1 void*)vn1, (AS3 void*)(&LB[8192 + nb + (wv * 2 + 1) * 512]), 16, 0, 0);
        kn0 += 4096; kn1 += 4096; vn0 += 64; vn1 += 64;
    }
    f32x16 s0, s1;
    __builtin_amdgcn_s_setprio(1);
    {
        bf16x8 a0 = *(const bf16x8*)(LB + BUF * 4096 + l31 * 64 + so[0]);
        bf16x8 a1 = *(const bf16x8*)(LB + BUF * 4096 + (32 + l31) * 64 + so[0]);
        s0 = __builtin_amdgcn_mfma_f32_32x32x16_bf16(a0, qf[0], Z, 0, 0, 0);
        s1 = __builtin_amdgcn_mfma_f32_32x32x16_bf16(a1, qf[0], Z, 0, 0, 0);
    }
#pragma unroll
    for (int dc = 1; dc < 4; dc++) {
        bf16x8 a0 = *(const bf16x8*)(LB + BUF * 4096 + l31 * 64 + so[dc]);
        bf16x8 a1 = *(const bf16x8*)(LB + BUF * 4096 + (32 + l31) * 64 + so[dc]);
        s0 = __builtin_amdgcn_mfma_f32_32x32x16_bf16(a0, qf[dc], s0, 0, 0, 0);
        s1 = __builtin_amdgcn_mfma_f32_32x32x16_bf16(a1, qf[dc], s1, 0, 0, 0);
    }
    __builtin_amdgcn_s_setprio(0);
#pragma unroll
    for (int r = 0; r < 16; r++) { s0[r] = EXP2(s0[r]); s1[r] = EXP2(s1[r]); }
#pragma unroll
    for (int r = 0; r < 8; r++) {
        unsigned u0, u1;
        asm("v_cvt_pk_bf16_f32 %0, %1, %2" : "=v"(u0) : "v"(s0[2 * r]), "v"(s0[2 * r + 1]));
        asm("v_cvt_pk_bf16_f32 %0, %1, %2" : "=v"(u1) : "v"(s1[2 * r]), "v"(s1[2 * r + 1]));
        s0[2 * r] = __uint_as_float(u0);
        s1[2 * r] = __uint_as_float(u1);
    }
    __builtin_amdgcn_s_setprio(1);
#pragma unroll
    for (int kc = 0; kc < 4; kc++) {
        const int bs = (kc & 1) * 8;
        bf16x8 pf;
        {
            float e0 = (kc < 2) ? s0[bs + 0] : s1[bs + 0];
            float e4 = (kc < 2) ? s0[bs + 4] : s1[bs + 4];
            float e2 = (kc < 2) ? s0[bs + 2] : s1[bs + 2];
            float e6 = (kc < 2) ? s0[bs + 6] : s1[bs + 6];
            auto uA = __builtin_amdgcn_permlane32_swap(__float_as_uint(e0), __float_as_uint(e4), false, false);
            auto uB = __builtin_amdgcn_permlane32_swap(__float_as_uint(e2), __float_as_uint(e6), false, false);
            u32x4 t; t.x = uA[0]; t.y = uB[0]; t.z = uA[1]; t.w = uB[1];
            pf = __builtin_bit_cast(bf16x8, t);
        }
        bf16x8 va  = *(const bf16x8*)(LB + 8192 + BUF * 4096 + l31 * 64 + so[kc]);
        bf16x8 vb2 = *(const bf16x8*)(LB + 8192 + BUF * 4096 + (32 + l31) * 64 + so[kc]);
        O0 = __builtin_amdgcn_mfma_f32_32x32x16_bf16(va,  pf, O0, 0, 0, 0);
        O1 = __builtin_amdgcn_mfma_f32_32x32x16_bf16(vb2, pf, O1, 0, 0, 0);
        Ss = __builtin_amdgcn_mfma_f32_32x32x16_bf16(ones, pf, Ss, 0, 0, 0);
    }
    __builtin_amdgcn_s_setprio(0);
    __syncthreads();
}

__global__ __launch_bounds__(256, 4) void attn_mfma_kernel(const unsigned short* __restrict__ qbp,
                                                           const unsigned short* __restrict__ kbp,
                                                           const unsigned short* __restrict__ vtp,
                                                           unsigned short* __restrict__ aout) {
    __shared__ unsigned short LB[4 * 4096];      // K0,K1,V0,V1 (32 KB)
    const int tid = threadIdx.x;
    const int wv = tid >> 6;       // 0..3
    const int l = tid & 63;
    const int l31 = l & 31, hi = l >> 5;

    const int wg = blockIdx.x;                    // 0..1023
    const int Lidx = (wg & 7) * 128 + (wg >> 3);  // 8 bh per XCD
    const int bh = Lidx >> 4;
    const int q0 = (Lidx & 15) * 128;

    const unsigned short* qp = qbp + (size_t)bh * (NN * HD);
    const unsigned short* kp = kbp + (size_t)bh * (NN * HD);
    const unsigned short* vp = vtp + (size_t)bh * (NN * HD);

    const int r0 = (wv * 2 + 0) * 8 + (l >> 3);
    const int r1 = (wv * 2 + 1) * 8 + (l >> 3);
    const int c0 = ((l & 7) ^ (r0 & 7)) * 8;
    const int c1 = ((l & 7) ^ (r1 & 7)) * 8;
    const unsigned short* kn0 = kp + r0 * HD + c0;
    const unsigned short* kn1 = kp + r1 * HD + c1;
    const unsigned short* vn0 = vp + (size_t)r0 * NN + c0;
    const unsigned short* vn1 = vp + (size_t)r1 * NN + c1;

    __builtin_amdgcn_global_load_lds((AS1 void*)kn0, (AS3 void*)(&LB[(wv * 2 + 0) * 512]), 16, 0, 0);
    __builtin_amdgcn_global_load_lds((AS1 void*)kn1, (AS3 void*)(&LB[(wv * 2 + 1) * 512]), 16, 0, 0);
    __builtin_amdgcn_global_load_lds((AS1 void*)vn0, (AS3 void*)(&LB[8192 + (wv * 2 + 0) * 512]), 16, 0, 0);
    __builtin_amdgcn_global_load_lds((AS1 void*)vn1, (AS3 void*)(&LB[8192 + (wv * 2 + 1) * 512]), 16, 0, 0);
    kn0 += 4096; kn1 += 4096; vn0 += 64; vn1 += 64;

    const unsigned short* qr = qp + (size_t)(q0 + wv * 32 + l31) * HD;
    bf16x8 qf[4];
#pragma unroll
    for (int dc = 0; dc < 4; dc++)
        qf[dc] = *(const bf16x8*)(qr + dc * 16 + hi * 8);

    int so[4];
#pragma unroll
    for (int i = 0; i < 4; i++) so[i] = ((2 * i + hi) ^ (l31 & 7)) * 8;

    f32x16 Z;
#pragma unroll
    for (int r = 0; r < 16; r++) Z[r] = 0.0f;
    f32x16 O0 = Z, O1 = Z, Ss = Z;
    bf16x8 ones;
#pragma unroll
    for (int j = 0; j < 8; j++) ones[j] = (short)0x3F80;  // bf16 1.0

    __syncthreads();

    for (int ktb = 0; ktb < NT; ktb += 2) {
        attn_iter<0>(LB, true, wv, l31, kn0, kn1, vn0, vn1, so, qf,
                     Z, ones, O0, O1, Ss);
        attn_iter<1>(LB, ktb + 2 < NT, wv, l31, kn0, kn1, vn0, vn1, so, qf,
                     Z, ones, O0, O1, Ss);
    }

    const int b_ = bh >> 4, hh = bh & 15;
    const float inv = 1.0f / Ss[0];
    const size_t mrow = (size_t)(b_ * NN + q0 + wv * 32 + l31) * CC + hh * HD;
#pragma unroll
    for (int rq = 0; rq < 4; rq++) {
        u16x4 o0, o1;
#pragma unroll
        for (int j = 0; j < 4; j++) {
            o0[j] = f2bf(O0[rq * 4 + j] * inv);
            o1[j] = f2bf(O1[rq * 4 + j] * inv);
        }
        *(u16x4*)(aout + mrow + rq * 8 + hi * 4) = o0;
        *(u16x4*)(aout + mrow + 32 + rq * 8 + hi * 4) = o1;
    }
}

// ---------------- kernel 6: proj GEMM (bf16 MFMA) + bias (2D grid) ----------------
__global__ __launch_bounds__(256) void proj_gemm_kernel(const unsigned short* __restrict__ A,
                                                        const unsigned short* __restrict__ Bw,
                                                        const float* __restrict__ bp,
                                                        float* __restrict__ out) {
    __shared__ unsigned short Asl[128 * 64];
    __shared__ unsigned short Bsl[128 * 64];
    const int tid = threadIdx.x;
    const int wv = tid >> 6, l = tid & 63;
    const int wm = wv >> 1, wn = wv & 1;
    const int lg = l >> 4, l15 = l & 15;
    const int m0 = blockIdx.x * 128, n0 = blockIdx.y * 128;

    f32x4 acc[4][4];
#pragma unroll
    for (int i = 0; i < 4; i++)
#pragma unroll
        for (int j = 0; j < 4; j++) acc[i][j] = f32x4{0.f, 0.f, 0.f, 0.f};

    for (int kt = 0; kt < CC; kt += 64) {
        __syncthreads();
#pragma unroll
        for (int i = 0; i < 4; i++) {
            int c = (wv * 4 + i) * 64 + l;
            int r = c >> 3, kc = c & 7;
            int sc = kt + ((kc ^ (r & 7)) * 8);
            __builtin_amdgcn_global_load_lds(
                (AS1 void*)(A + (size_t)(m0 + r) * CC + sc),
                (AS3 void*)(&Asl[(wv * 4 + i) * 512]), 16, 0, 0);
            __builtin_amdgcn_global_load_lds(
                (AS1 void*)(Bw + (size_t)(n0 + r) * CC + sc),
                (AS3 void*)(&Bsl[(wv * 4 + i) * 512]), 16, 0, 0);
        }
        __syncthreads();
#pragma unroll
        for (int kc = 0; kc < 2; kc++) {
            bf16x8 af[4], bfr[4];
#pragma unroll
            for (int mi = 0; mi < 4; mi++) {
                int r = wm * 64 + mi * 16 + l15;
                af[mi] = *(const bf16x8*)(&Asl[r * 64 + (((kc * 4 + lg) ^ (r & 7)) * 8)]);
            }
#pragma unroll
            for (int nj = 0; nj < 4; nj++) {
                int r = wn * 64 + nj * 16 + l15;
                bfr[nj] = *(const bf16x8*)(&Bsl[r * 64 + (((kc * 4 + lg) ^ (r & 7)) * 8)]);
            }
#pragma unroll
            for (int mi = 0; mi < 4; mi++)
#pragma unroll
                for (int nj = 0; nj < 4; nj++)
                    acc[mi][nj] = __builtin_amdgcn_mfma_f32_16x16x32_bf16(af[mi], bfr[nj], acc[mi][nj], 0, 0, 0);
        }
    }
    float bias[4];
#pragma unroll
    for (int nj = 0; nj < 4; nj++) bias[nj] = bp[n0 + wn * 64 + nj * 16 + l15];
#pragma unroll
    for (int mi = 0; mi < 4; mi++)
#pragma unroll
        for (int nj = 0; nj < 4; nj++) {
            int oc = n0 + wn * 64 + nj * 16 + l15;
#pragma unroll
            for (int reg = 0; reg < 4; reg++) {
                int m = m0 + wm * 64 + mi * 16 + lg * 4 + reg;
                out[(size_t)m * CC + oc] = acc[mi][nj][reg] + bias[nj];
            }
        }
}

extern "C" void kernel_launch(void* const* d_in, const int* in_sizes, int n_in,
                              void* d_out, int out_size, void* d_ws, size_t ws_size,
                              hipStream_t stream) {
    const float* x      = (const float*)d_in[0];
    const float* t_x    = (const float*)d_in[1];
    const float* t_y    = (const float*)d_in[2];
    const float* t_z    = (const float*)d_in[3];
    const float* w_qkv  = (const float*)d_in[4];
    const float* w_proj = (const float*)d_in[5];
    const float* b_proj = (const float*)d_in[6];
    const float* freqs  = (const float*)d_in[7];
    float* out = (float*)d_out;

    unsigned short* xb     = (unsigned short*)d_ws;            // MM*CC
    unsigned short* wqkvb  = xb + (size_t)MM * CC;             // K3*CC
    unsigned short* wprojb = wqkvb + (size_t)K3 * CC;          // CC*CC
    unsigned short* qbuf   = wprojb + (size_t)CC * CC;         // B*H*N*HD
    unsigned short* kbuf   = qbuf + (size_t)BB * HH * NN * HD;
    unsigned short* vbT    = kbuf + (size_t)BB * HH * NN * HD; // [bh][d][n]
    unsigned short* attnb  = vbT + (size_t)BB * HH * NN * HD;
    float* csT   = (float*)(attnb + (size_t)MM * CC);          // NN*NF float2
    float* tnorm = csT + (size_t)2 * NN * NF;

    tnorm_kernel<<<3, 256, 0, stream>>>(t_x, t_y, t_z, tnorm);
    angle_kernel<<<NN, 512, 0, stream>>>(freqs, tnorm, csT);
    cvt_kernel<<<(MM * CC) / 2048, 256, 0, stream>>>(x, xb, MM * CC);
    cvt_kernel<<<(K3 * CC) / 2048, 256, 0, stream>>>(w_qkv, wqkvb, K3 * CC);
    cvt_kernel<<<(CC * CC) / 2048, 256, 0, stream>>>(w_proj, wprojb, CC * CC);
    qkv_gemm_kernel<<<dim3(MM / 128, K3 / 128), 256, 0, stream>>>(xb, wqkvb, csT,
                                                                  qbuf, kbuf, vbT);
    attn_mfma_kernel<<<1024, 256, 0, stream>>>(qbuf, kbuf, vbT, attnb);
    proj_gemm_kernel<<<dim3(MM / 128, CC / 128), 256, 0, stream>>>(attnb, wprojb, b_proj, out);
}

// Round 13
// 206.926 us; speedup vs baseline: 1.1144x; 1.0761x over previous
//
#include <hip/hip_runtime.h>
#include <math.h>

#define BB 4
#define NN 2048
#define CC 1024
#define HH 16
#define HD 64
#define HALF 32
#define MM (BB*NN)     // 8192
#define K3 (3*CC)      // 3072
#define NF (HH*HALF)   // 512
#define NT (NN/64)     // 32 k-tiles (attn)

typedef __attribute__((ext_vector_type(8))) short bf16x8;
typedef __attribute__((ext_vector_type(4))) float f32x4;
typedef __attribute__((ext_vector_type(16))) float f32x16;
typedef __attribute__((ext_vector_type(4))) unsigned short u16x4;
typedef __attribute__((ext_vector_type(8))) unsigned short u16x8;
typedef __attribute__((ext_vector_type(4))) unsigned int u32x4;

#if __has_builtin(__builtin_amdgcn_exp2f)
#define EXP2(x) __builtin_amdgcn_exp2f(x)
#else
#define EXP2(x) exp2f(x)
#endif
#define AS1 __attribute__((address_space(1)))
#define AS3 __attribute__((address_space(3)))

__device__ __forceinline__ unsigned short f2bf(float f) {
    unsigned int u = __float_as_uint(f);
    unsigned int r = (u + 0x7FFFu + ((u >> 16) & 1u)) >> 16;
    return (unsigned short)r;
}

// ---------------- kernel 1: normalize t arrays ----------------
__global__ __launch_bounds__(256) void tnorm_kernel(const float* t_x, const float* t_y,
                                                    const float* t_z, float* tnorm) {
    int a = blockIdx.x;
    const float* t = (a == 0) ? t_x : ((a == 1) ? t_y : t_z);
    __shared__ float smn[256], smx[256];
    float mn = 1e30f, mx = -1e30f;
    for (int i = threadIdx.x; i < NN; i += 256) {
        float v = t[i];
        mn = fminf(mn, v);
        mx = fmaxf(mx, v);
    }
    smn[threadIdx.x] = mn; smx[threadIdx.x] = mx;
    __syncthreads();
    for (int s = 128; s > 0; s >>= 1) {
        if (threadIdx.x < s) {
            smn[threadIdx.x] = fminf(smn[threadIdx.x], smn[threadIdx.x + s]);
            smx[threadIdx.x] = fmaxf(smx[threadIdx.x], smx[threadIdx.x + s]);
        }
        __syncthreads();
    }
    float lo = smn[0];
    float sc = 32.0f / (smx[0] - lo + 1e-8f);
    for (int i = threadIdx.x; i < NN; i += 256)
        tnorm[a * NN + i] = (t[i] - lo) * sc;
}

// ---------------- kernel 2: angle -> interleaved {cos,sin} table (float2) ----------------
__global__ __launch_bounds__(512) void angle_kernel(const float* freqs, const float* tnorm,
                                                    float* csT) {
    int n = blockIdx.x;
    int hf = threadIdx.x;  // 0..511
    float ang = tnorm[n] * freqs[hf]
              + tnorm[NN + n] * freqs[NF + hf]
              + tnorm[2 * NN + n] * freqs[2 * NF + hf];
    float2 cs;
    cs.x = cosf(ang);
    cs.y = sinf(ang);
    *(float2*)(csT + 2 * ((size_t)n * NF + hf)) = cs;
}

// ---------------- kernel 3: fused f32 -> bf16 convert for x, w_qkv, w_proj ----------------
#define XBLK (MM * CC / 2048)          // 4096
#define WQBLK (K3 * CC / 2048)         // 1536
#define WPBLK (CC * CC / 2048)         // 512
__global__ __launch_bounds__(256) void cvt_all_kernel(const float* __restrict__ x,
                                                      const float* __restrict__ wq,
                                                      const float* __restrict__ wp,
                                                      unsigned short* __restrict__ xb,
                                                      unsigned short* __restrict__ wqb,
                                                      unsigned short* __restrict__ wpb) {
    int bid = blockIdx.x;
    const float* src;
    unsigned short* dst;
    if (bid < XBLK) { src = x; dst = xb; }
    else if (bid < XBLK + WQBLK) { src = wq; dst = wqb; bid -= XBLK; }
    else { src = wp; dst = wpb; bid -= XBLK + WQBLK; }
    int i = (bid * 256 + threadIdx.x) * 8;
    float4 a = *(const float4*)(src + i);
    float4 b = *(const float4*)(src + i + 4);
    u16x8 o;
    o[0] = f2bf(a.x); o[1] = f2bf(a.y); o[2] = f2bf(a.z); o[3] = f2bf(a.w);
    o[4] = f2bf(b.x); o[5] = f2bf(b.y); o[6] = f2bf(b.z); o[7] = f2bf(b.w);
    *(u16x8*)(dst + i) = o;
}

// ---------------- kernel 4: QKV GEMM (bf16 MFMA) + fused RoPE (2D grid, verified) ----------------
__global__ __launch_bounds__(256) void qkv_gemm_kernel(const unsigned short* __restrict__ A,
                                                       const unsigned short* __restrict__ Bw,
                                                       const float* __restrict__ csT,
                                                       unsigned short* __restrict__ qb,
                                                       unsigned short* __restrict__ kb,
                                                       unsigned short* __restrict__ vbT) {
    __shared__ unsigned short Asl[128 * 64];
    __shared__ unsigned short Bsl[128 * 64];
    const int tid = threadIdx.x;
    const int wv = tid >> 6, l = tid & 63;
    const int wm = wv >> 1, wn = wv & 1;
    const int lg = l >> 4, l15 = l & 15;
    const int m0 = blockIdx.x * 128, n0 = blockIdx.y * 128;

    f32x4 acc[4][4];
#pragma unroll
    for (int i = 0; i < 4; i++)
#pragma unroll
        for (int j = 0; j < 4; j++) acc[i][j] = f32x4{0.f, 0.f, 0.f, 0.f};

    for (int kt = 0; kt < CC; kt += 64) {
        __syncthreads();
#pragma unroll
        for (int i = 0; i < 4; i++) {
            int c = (wv * 4 + i) * 64 + l;
            int r = c >> 3, kc = c & 7;
            int sc = kt + ((kc ^ (r & 7)) * 8);
            __builtin_amdgcn_global_load_lds(
                (AS1 void*)(A + (size_t)(m0 + r) * CC + sc),
                (AS3 void*)(&Asl[(wv * 4 + i) * 512]), 16, 0, 0);
            __builtin_amdgcn_global_load_lds(
                (AS1 void*)(Bw + (size_t)(n0 + r) * CC + sc),
                (AS3 void*)(&Bsl[(wv * 4 + i) * 512]), 16, 0, 0);
        }
        __syncthreads();
#pragma unroll
        for (int kc = 0; kc < 2; kc++) {
            bf16x8 af[4], bfr[4];
#pragma unroll
            for (int mi = 0; mi < 4; mi++) {
                int r = wm * 64 + mi * 16 + l15;
                af[mi] = *(const bf16x8*)(&Asl[r * 64 + (((kc * 4 + lg) ^ (r & 7)) * 8)]);
            }
#pragma unroll
            for (int nj = 0; nj < 4; nj++) {
                int r = wn * 64 + nj * 16 + l15;
                bfr[nj] = *(const bf16x8*)(&Bsl[r * 64 + (((kc * 4 + lg) ^ (r & 7)) * 8)]);
            }
#pragma unroll
            for (int mi = 0; mi < 4; mi++)
#pragma unroll
                for (int nj = 0; nj < 4; nj++)
                    acc[mi][nj] = __builtin_amdgcn_mfma_f32_16x16x32_bf16(af[mi], bfr[nj], acc[mi][nj], 0, 0, 0);
        }
    }
    // epilogue: RoPE for q/k ([bh][n][d]); v transposed ([bh][d][n])
    const int b_ = m0 >> 11;
    const int nrow0 = (m0 & (NN - 1));
#pragma unroll
    for (int nj = 0; nj < 4; nj++) {
        int oc = n0 + wn * 64 + nj * 16 + l15;
        int s = oc >> 10;
        int rr = oc & 1023;
        int h = rr >> 6;
        int d = rr & 63;
        int f = d >> 1;
#pragma unroll
        for (int mi = 0; mi < 4; mi++) {
            f32x4 v = acc[mi][nj];
            if (s == 2) {
                u16x4 vv;
#pragma unroll
                for (int reg = 0; reg < 4; reg++) vv[reg] = f2bf(v[reg]);
                int nb = nrow0 + wm * 64 + mi * 16 + lg * 4;
                *(u16x4*)(vbT + ((size_t)((b_ * HH + h) * HD + d)) * NN + nb) = vv;
            } else {
#pragma unroll
                for (int reg = 0; reg < 4; reg++) {
                    int m = m0 + wm * 64 + mi * 16 + lg * 4 + reg;
                    int n = m & (NN - 1);
                    float val = v[reg];
                    float partner = __shfl_xor(val, 1);
                    size_t base = (((size_t)(b_ * HH + h)) * NN + n) * HD + d;
                    float2 cs2 = *(const float2*)(csT + 2 * ((size_t)n * NF + h * HALF + f));
                    float res = ((d & 1) == 0) ? (val * cs2.x - partner * cs2.y)
                                               : (val * cs2.x + partner * cs2.y);
                    if (s == 0) res *= 0.18033688011112043f;  // 0.125 * log2(e)
                    (s == 0 ? qb : kb)[base] = f2bf(res);
                }
            }
        }
    }
}

// ---------------- kernel 5: flash attention (verified round-7 version, exact) ----------------
template<int BUF>
__device__ __forceinline__ void attn_iter(
    unsigned short* LB, bool do_stage, int wv, int l31,
    const unsigned short*& kn0, const unsigned short*& kn1,
    const unsigned short*& vn0, const unsigned short*& vn1,
    const int (&so)[4], const bf16x8 (&qfA)[4], const bf16x8 (&qfB)[4],
    const f32x16& Z, const bf16x8& ones,
    f32x16& OA0, f32x16& OA1, f32x16& OB0, f32x16& OB1,
    f32x16& SsA, f32x16& SsB) {
    if (do_stage) {
        const int nb = (BUF ^ 1) * 4096;
        __builtin_amdgcn_global_load_lds((AS1 void*)kn0, (AS3 void*)(&LB[nb + (wv * 2 + 0) * 512]), 16, 0, 0);
        __builtin_amdgcn_global_load_lds((AS1 void*)kn1, (AS3 void*)(&LB[nb + (wv * 2 + 1) * 512]), 16, 0, 0);
        __builtin_amdgcn_global_load_lds((AS1 void*)vn0, (AS3 void*)(&LB[8192 + nb + (wv * 2 + 0) * 512]), 16, 0, 0);
        __builtin_amdgcn_global_load_lds((AS1 void*)vn1, (AS3 void*)(&LB[8192 + nb + (wv * 2 + 1) * 512]), 16, 0, 0);
        kn0 += 4096; kn1 += 4096; vn0 += 64; vn1 += 64;
    }
    f32x16 sA0, sA1, sB0, sB1;
    __builtin_amdgcn_s_setprio(1);
    {
        bf16x8 a0 = *(const bf16x8*)(LB + BUF * 4096 + l31 * 64 + so[0]);
        bf16x8 a1 = *(const bf16x8*)(LB + BUF * 4096 + (32 + l31) * 64 + so[0]);
        sA0 = __builtin_amdgcn_mfma_f32_32x32x16_bf16(a0, qfA[0], Z, 0, 0, 0);
        sA1 = __builtin_amdgcn_mfma_f32_32x32x16_bf16(a1, qfA[0], Z, 0, 0, 0);
        sB0 = __builtin_amdgcn_mfma_f32_32x32x16_bf16(a0, qfB[0], Z, 0, 0, 0);
        sB1 = __builtin_amdgcn_mfma_f32_32x32x16_bf16(a1, qfB[0], Z, 0, 0, 0);
    }
#pragma unroll
    for (int dc = 1; dc < 4; dc++) {
        bf16x8 a0 = *(const bf16x8*)(LB + BUF * 4096 + l31 * 64 + so[dc]);
        bf16x8 a1 = *(const bf16x8*)(LB + BUF * 4096 + (32 + l31) * 64 + so[dc]);
        sA0 = __builtin_amdgcn_mfma_f32_32x32x16_bf16(a0, qfA[dc], sA0, 0, 0, 0);
        sA1 = __builtin_amdgcn_mfma_f32_32x32x16_bf16(a1, qfA[dc], sA1, 0, 0, 0);
        sB0 = __builtin_amdgcn_mfma_f32_32x32x16_bf16(a0, qfB[dc], sB0, 0, 0, 0);
        sB1 = __builtin_amdgcn_mfma_f32_32x32x16_bf16(a1, qfB[dc], sB1, 0, 0, 0);
    }
    __builtin_amdgcn_s_setprio(0);
#pragma unroll
    for (int r = 0; r < 16; r++) {
        sA0[r] = EXP2(sA0[r]); sA1[r] = EXP2(sA1[r]);
        sB0[r] = EXP2(sB0[r]); sB1[r] = EXP2(sB1[r]);
    }
#pragma unroll
    for (int r = 0; r < 8; r++) {
        unsigned u0, u1, u2, u3;
        asm("v_cvt_pk_bf16_f32 %0, %1, %2" : "=v"(u0) : "v"(sA0[2 * r]), "v"(sA0[2 * r + 1]));
        asm("v_cvt_pk_bf16_f32 %0, %1, %2" : "=v"(u1) : "v"(sA1[2 * r]), "v"(sA1[2 * r + 1]));
        asm("v_cvt_pk_bf16_f32 %0, %1, %2" : "=v"(u2) : "v"(sB0[2 * r]), "v"(sB0[2 * r + 1]));
        asm("v_cvt_pk_bf16_f32 %0, %1, %2" : "=v"(u3) : "v"(sB1[2 * r]), "v"(sB1[2 * r + 1]));
        sA0[2 * r] = __uint_as_float(u0);
        sA1[2 * r] = __uint_as_float(u1);
        sB0[2 * r] = __uint_as_float(u2);
        sB1[2 * r] = __uint_as_float(u3);
    }
    __builtin_amdgcn_s_setprio(1);
#pragma unroll
    for (int kc = 0; kc < 4; kc++) {
        const int bs = (kc & 1) * 8;
        bf16x8 pfA, pfB;
        {
            float e0 = (kc < 2) ? sA0[bs + 0] : sA1[bs + 0];
            float e4 = (kc < 2) ? sA0[bs + 4] : sA1[bs + 4];
            float e2 = (kc < 2) ? sA0[bs + 2] : sA1[bs + 2];
            float e6 = (kc < 2) ? sA0[bs + 6] : sA1[bs + 6];
            auto uA = __builtin_amdgcn_permlane32_swap(__float_as_uint(e0), __float_as_uint(e4), false, false);
            auto uB = __builtin_amdgcn_permlane32_swap(__float_as_uint(e2), __float_as_uint(e6), false, false);
            u32x4 t; t.x = uA[0]; t.y = uB[0]; t.z = uA[1]; t.w = uB[1];
            pfA = __builtin_bit_cast(bf16x8, t);
        }
        {
            float e0 = (kc < 2) ? sB0[bs + 0] : sB1[bs + 0];
            float e4 = (kc < 2) ? sB0[bs + 4] : sB1[bs + 4];
            float e2 = (kc < 2) ? sB0[bs + 2] : sB1[bs + 2];
            float e6 = (kc < 2) ? sB0[bs + 6] : sB1[bs + 6];
            auto uA = __builtin_amdgcn_permlane32_swap(__float_as_uint(e0), __float_as_uint(e4), false, false);
            auto uB = __builtin_amdgcn_permlane32_swap(__float_as_uint(e2), __float_as_uint(e6), false, false);
            u32x4 t; t.x = uA[0]; t.y = uB[0]; t.z = uA[1]; t.w = uB[1];
            pfB = __builtin_bit_cast(bf16x8, t);
        }
        bf16x8 va  = *(const bf16x8*)(LB + 8192 + BUF * 4096 + l31 * 64 + so[kc]);
        bf16x8 vb2 = *(const bf16x8*)(LB + 8192 + BUF * 4096 + (32 + l31) * 64 + so[kc]);
        OA0 = __builtin_amdgcn_mfma_f32_32x32x16_bf16(va,  pfA, OA0, 0, 0, 0);
        OA1 = __builtin_amdgcn_mfma_f32_32x32x16_bf16(vb2, pfA, OA1, 0, 0, 0);
        OB0 = __builtin_amdgcn_mfma_f32_32x32x16_bf16(va,  pfB, OB0, 0, 0, 0);
        OB1 = __builtin_amdgcn_mfma_f32_32x32x16_bf16(vb2, pfB, OB1, 0, 0, 0);
        SsA = __builtin_amdgcn_mfma_f32_32x32x16_bf16(ones, pfA, SsA, 0, 0, 0);
        SsB = __builtin_amdgcn_mfma_f32_32x32x16_bf16(ones, pfB, SsB, 0, 0, 0);
    }
    __builtin_amdgcn_s_setprio(0);
    __syncthreads();
}

__global__ __launch_bounds__(256, 2) void attn_mfma_kernel(const unsigned short* __restrict__ qbp,
                                                           const unsigned short* __restrict__ kbp,
                                                           const unsigned short* __restrict__ vtp,
                                                           unsigned short* __restrict__ aout) {
    __shared__ unsigned short LB[4 * 4096];      // K0,K1,V0,V1
    const int tid = threadIdx.x;
    const int wv = tid >> 6;       // 0..3
    const int l = tid & 63;
    const int l31 = l & 31, hi = l >> 5;

    const int wg = blockIdx.x;                    // 0..511
    const int Lidx = (wg & 7) * 64 + (wg >> 3);
    const int bh = Lidx >> 3;
    const int q0 = (Lidx & 7) * 256;

    const unsigned short* qp = qbp + (size_t)bh * (NN * HD);
    const unsigned short* kp = kbp + (size_t)bh * (NN * HD);
    const unsigned short* vp = vtp + (size_t)bh * (NN * HD);

    const int r0 = (wv * 2 + 0) * 8 + (l >> 3);
    const int r1 = (wv * 2 + 1) * 8 + (l >> 3);
    const int c0 = ((l & 7) ^ (r0 & 7)) * 8;
    const int c1 = ((l & 7) ^ (r1 & 7)) * 8;
    const unsigned short* kn0 = kp + r0 * HD + c0;
    const unsigned short* kn1 = kp + r1 * HD + c1;
    const unsigned short* vn0 = vp + (size_t)r0 * NN + c0;
    const unsigned short* vn1 = vp + (size_t)r1 * NN + c1;

    __builtin_amdgcn_global_load_lds((AS1 void*)kn0, (AS3 void*)(&LB[(wv * 2 + 0) * 512]), 16, 0, 0);
    __builtin_amdgcn_global_load_lds((AS1 void*)kn1, (AS3 void*)(&LB[(wv * 2 + 1) * 512]), 16, 0, 0);
    __builtin_amdgcn_global_load_lds((AS1 void*)vn0, (AS3 void*)(&LB[8192 + (wv * 2 + 0) * 512]), 16, 0, 0);
    __builtin_amdgcn_global_load_lds((AS1 void*)vn1, (AS3 void*)(&LB[8192 + (wv * 2 + 1) * 512]), 16, 0, 0);
    kn0 += 4096; kn1 += 4096; vn0 += 64; vn1 += 64;

    const unsigned short* qr = qp + (size_t)(q0 + wv * 64 + l31) * HD;
    bf16x8 qfA[4], qfB[4];
#pragma unroll
    for (int dc = 0; dc < 4; dc++) {
        qfA[dc] = *(const bf16x8*)(qr + dc * 16 + hi * 8);
        qfB[dc] = *(const bf16x8*)(qr + 32 * HD + dc * 16 + hi * 8);
    }

    int so[4];
#pragma unroll
    for (int i = 0; i < 4; i++) so[i] = ((2 * i + hi) ^ (l31 & 7)) * 8;

    f32x16 Z;
#pragma unroll
    for (int r = 0; r < 16; r++) Z[r] = 0.0f;
    f32x16 OA0 = Z, OA1 = Z, OB0 = Z, OB1 = Z, SsA = Z, SsB = Z;
    bf16x8 ones;
#pragma unroll
    for (int j = 0; j < 8; j++) ones[j] = (short)0x3F80;  // bf16 1.0

    __syncthreads();

    for (int ktb = 0; ktb < NT; ktb += 2) {
        attn_iter<0>(LB, true, wv, l31, kn0, kn1, vn0, vn1, so, qfA, qfB,
                     Z, ones, OA0, OA1, OB0, OB1, SsA, SsB);
        attn_iter<1>(LB, ktb + 2 < NT, wv, l31, kn0, kn1, vn0, vn1, so, qfA, qfB,
                     Z, ones, OA0, OA1, OB0, OB1, SsA, SsB);
    }

    const int b_ = bh >> 4, hh = bh & 15;
    const float invA = 1.0f / SsA[0], invB = 1.0f / SsB[0];
    const size_t mrowA = (size_t)(b_ * NN + q0 + wv * 64 + l31) * CC + hh * HD;
    const size_t mrowB = mrowA + (size_t)32 * CC;
#pragma unroll
    for (int rq = 0; rq < 4; rq++) {
        u16x4 a0, a1, b0, b1;
#pragma unroll
        for (int j = 0; j < 4; j++) {
            a0[j] = f2bf(OA0[rq * 4 + j] * invA);
            a1[j] = f2bf(OA1[rq * 4 + j] * invA);
            b0[j] = f2bf(OB0[rq * 4 + j] * invB);
            b1[j] = f2bf(OB1[rq * 4 + j] * invB);
        }
        *(u16x4*)(aout + mrowA + rq * 8 + hi * 4) = a0;
        *(u16x4*)(aout + mrowA + 32 + rq * 8 + hi * 4) = a1;
        *(u16x4*)(aout + mrowB + rq * 8 + hi * 4) = b0;
        *(u16x4*)(aout + mrowB + 32 + rq * 8 + hi * 4) = b1;
    }
}

// ---------------- kernel 6: proj GEMM (bf16 MFMA) + bias (2D grid) ----------------
__global__ __launch_bounds__(256) void proj_gemm_kernel(const unsigned short* __restrict__ A,
                                                        const unsigned short* __restrict__ Bw,
                                                        const float* __restrict__ bp,
                                                        float* __restrict__ out) {
    __shared__ unsigned short Asl[128 * 64];
    __shared__ unsigned short Bsl[128 * 64];
    const int tid = threadIdx.x;
    const int wv = tid >> 6, l = tid & 63;
    const int wm = wv >> 1, wn = wv & 1;
    const int lg = l >> 4, l15 = l & 15;
    const int m0 = blockIdx.x * 128, n0 = blockIdx.y * 128;

    f32x4 acc[4][4];
#pragma unroll
    for (int i = 0; i < 4; i++)
#pragma unroll
        for (int j = 0; j < 4; j++) acc[i][j] = f32x4{0.f, 0.f, 0.f, 0.f};

    for (int kt = 0; kt < CC; kt += 64) {
        __syncthreads();
#pragma unroll
        for (int i = 0; i < 4; i++) {
            int c = (wv * 4 + i) * 64 + l;
            int r = c >> 3, kc = c & 7;
            int sc = kt + ((kc ^ (r & 7)) * 8);
            __builtin_amdgcn_global_load_lds(
                (AS1 void*)(A + (size_t)(m0 + r) * CC + sc),
                (AS3 void*)(&Asl[(wv * 4 + i) * 512]), 16, 0, 0);
            __builtin_amdgcn_global_load_lds(
                (AS1 void*)(Bw + (size_t)(n0 + r) * CC + sc),
                (AS3 void*)(&Bsl[(wv * 4 + i) * 512]), 16, 0, 0);
        }
        __syncthreads();
#pragma unroll
        for (int kc = 0; kc < 2; kc++) {
            bf16x8 af[4], bfr[4];
#pragma unroll
            for (int mi = 0; mi < 4; mi++) {
                int r = wm * 64 + mi * 16 + l15;
                af[mi] = *(const bf16x8*)(&Asl[r * 64 + (((kc * 4 + lg) ^ (r & 7)) * 8)]);
            }
#pragma unroll
            for (int nj = 0; nj < 4; nj++) {
                int r = wn * 64 + nj * 16 + l15;
                bfr[nj] = *(const bf16x8*)(&Bsl[r * 64 + (((kc * 4 + lg) ^ (r & 7)) * 8)]);
            }
#pragma unroll
            for (int mi = 0; mi < 4; mi++)
#pragma unroll
                for (int nj = 0; nj < 4; nj++)
                    acc[mi][nj] = __builtin_amdgcn_mfma_f32_16x16x32_bf16(af[mi], bfr[nj], acc[mi][nj], 0, 0, 0);
        }
    }
    float bias[4];
#pragma unroll
    for (int nj = 0; nj < 4; nj++) bias[nj] = bp[n0 + wn * 64 + nj * 16 + l15];
#pragma unroll
    for (int mi = 0; mi < 4; mi++)
#pragma unroll
        for (int nj = 0; nj < 4; nj++) {
            int oc = n0 + wn * 64 + nj * 16 + l15;
#pragma unroll
            for (int reg = 0; reg < 4; reg++) {
                int m = m0 + wm * 64 + mi * 16 + lg * 4 + reg;
                out[(size_t)m * CC + oc] = acc[mi][nj][reg] + bias[nj];
            }
        }
}

extern "C" void kernel_launch(void* const* d_in, const int* in_sizes, int n_in,
                              void* d_out, int out_size, void* d_ws, size_t ws_size,
                              hipStream_t stream) {
    const float* x      = (const float*)d_in[0];
    const float* t_x    = (const float*)d_in[1];
    const float* t_y    = (const float*)d_in[2];
    const float* t_z    = (const float*)d_in[3];
    const float* w_qkv  = (const float*)d_in[4];
    const float* w_proj = (const float*)d_in[5];
    const float* b_proj = (const float*)d_in[6];
    const float* freqs  = (const float*)d_in[7];
    float* out = (float*)d_out;

    unsigned short* xb     = (unsigned short*)d_ws;            // MM*CC
    unsigned short* wqkvb  = xb + (size_t)MM * CC;             // K3*CC
    unsigned short* wprojb = wqkvb + (size_t)K3 * CC;          // CC*CC
    unsigned short* qbuf   = wprojb + (size_t)CC * CC;         // B*H*N*HD
    unsigned short* kbuf   = qbuf + (size_t)BB * HH * NN * HD;
    unsigned short* vbT    = kbuf + (size_t)BB * HH * NN * HD; // [bh][d][n]
    unsigned short* attnb  = vbT + (size_t)BB * HH * NN * HD;
    float* csT   = (float*)(attnb + (size_t)MM * CC);          // NN*NF float2
    float* tnorm = csT + (size_t)2 * NN * NF;

    tnorm_kernel<<<3, 256, 0, stream>>>(t_x, t_y, t_z, tnorm);
    angle_kernel<<<NN, 512, 0, stream>>>(freqs, tnorm, csT);
    cvt_all_kernel<<<XBLK + WQBLK + WPBLK, 256, 0, stream>>>(x, w_qkv, w_proj,
                                                             xb, wqkvb, wprojb);
    qkv_gemm_kernel<<<dim3(MM / 128, K3 / 128), 256, 0, stream>>>(xb, wqkvb, csT,
                                                                  qbuf, kbuf, vbT);
    attn_mfma_kernel<<<512, 256, 0, stream>>>(qbuf, kbuf, vbT, attnb);
    proj_gemm_kernel<<<dim3(MM / 128, CC / 128), 256, 0, stream>>>(attnb, wprojb, b_proj, out);
}

// Round 14
// 199.880 us; speedup vs baseline: 1.1537x; 1.0353x over previous
//
#include <hip/hip_runtime.h>
#include <math.h>

#define BB 4
#define NN 2048
#define CC 1024
#define HH 16
#define HD 64
#define HALF 32
#define MM (BB*NN)     // 8192
#define K3 (3*CC)      // 3072
#define NF (HH*HALF)   // 512
#define NT (NN/64)     // 32 k-tiles (attn)

typedef __attribute__((ext_vector_type(8))) short bf16x8;
typedef __attribute__((ext_vector_type(4))) float f32x4;
typedef __attribute__((ext_vector_type(16))) float f32x16;
typedef __attribute__((ext_vector_type(4))) unsigned short u16x4;
typedef __attribute__((ext_vector_type(8))) unsigned short u16x8;
typedef __attribute__((ext_vector_type(4))) unsigned int u32x4;

#if __has_builtin(__builtin_amdgcn_exp2f)
#define EXP2(x) __builtin_amdgcn_exp2f(x)
#else
#define EXP2(x) exp2f(x)
#endif
#define AS1 __attribute__((address_space(1)))
#define AS3 __attribute__((address_space(3)))

__device__ __forceinline__ unsigned short f2bf(float f) {
    unsigned int u = __float_as_uint(f);
    unsigned int r = (u + 0x7FFFu + ((u >> 16) & 1u)) >> 16;
    return (unsigned short)r;
}

// ---------------- kernel 1: normalize t arrays ----------------
__global__ __launch_bounds__(256) void tnorm_kernel(const float* t_x, const float* t_y,
                                                    const float* t_z, float* tnorm) {
    int a = blockIdx.x;
    const float* t = (a == 0) ? t_x : ((a == 1) ? t_y : t_z);
    __shared__ float smn[256], smx[256];
    float mn = 1e30f, mx = -1e30f;
    for (int i = threadIdx.x; i < NN; i += 256) {
        float v = t[i];
        mn = fminf(mn, v);
        mx = fmaxf(mx, v);
    }
    smn[threadIdx.x] = mn; smx[threadIdx.x] = mx;
    __syncthreads();
    for (int s = 128; s > 0; s >>= 1) {
        if (threadIdx.x < s) {
            smn[threadIdx.x] = fminf(smn[threadIdx.x], smn[threadIdx.x + s]);
            smx[threadIdx.x] = fmaxf(smx[threadIdx.x], smx[threadIdx.x + s]);
        }
        __syncthreads();
    }
    float lo = smn[0];
    float sc = 32.0f / (smx[0] - lo + 1e-8f);
    for (int i = threadIdx.x; i < NN; i += 256)
        tnorm[a * NN + i] = (t[i] - lo) * sc;
}

// ---------------- kernel 2: angle -> interleaved {cos,sin} table (float2) ----------------
__global__ __launch_bounds__(512) void angle_kernel(const float* freqs, const float* tnorm,
                                                    float* csT) {
    int n = blockIdx.x;
    int hf = threadIdx.x;  // 0..511
    float ang = tnorm[n] * freqs[hf]
              + tnorm[NN + n] * freqs[NF + hf]
              + tnorm[2 * NN + n] * freqs[2 * NF + hf];
    float2 cs;
    cs.x = cosf(ang);
    cs.y = sinf(ang);
    *(float2*)(csT + 2 * ((size_t)n * NF + hf)) = cs;
}

// ---------------- kernel 3: fused f32 -> bf16 convert for x, w_qkv, w_proj ----------------
#define XBLK (MM * CC / 2048)          // 4096
#define WQBLK (K3 * CC / 2048)         // 1536
#define WPBLK (CC * CC / 2048)         // 512
__global__ __launch_bounds__(256) void cvt_all_kernel(const float* __restrict__ x,
                                                      const float* __restrict__ wq,
                                                      const float* __restrict__ wp,
                                                      unsigned short* __restrict__ xb,
                                                      unsigned short* __restrict__ wqb,
                                                      unsigned short* __restrict__ wpb) {
    int bid = blockIdx.x;
    const float* src;
    unsigned short* dst;
    if (bid < XBLK) { src = x; dst = xb; }
    else if (bid < XBLK + WQBLK) { src = wq; dst = wqb; bid -= XBLK; }
    else { src = wp; dst = wpb; bid -= XBLK + WQBLK; }
    int i = (bid * 256 + threadIdx.x) * 8;
    float4 a = *(const float4*)(src + i);
    float4 b = *(const float4*)(src + i + 4);
    u16x8 o;
    o[0] = f2bf(a.x); o[1] = f2bf(a.y); o[2] = f2bf(a.z); o[3] = f2bf(a.w);
    o[4] = f2bf(b.x); o[5] = f2bf(b.y); o[6] = f2bf(b.z); o[7] = f2bf(b.w);
    *(u16x8*)(dst + i) = o;
}

// ---------------- kernel 4: QKV GEMM, dbuf + counted vmcnt pipeline + fused RoPE ----------------
__global__ __launch_bounds__(256) void qkv_gemm_kernel(const unsigned short* __restrict__ A,
                                                       const unsigned short* __restrict__ Bw,
                                                       const float* __restrict__ csT,
                                                       unsigned short* __restrict__ qb,
                                                       unsigned short* __restrict__ kb,
                                                       unsigned short* __restrict__ vbT) {
    __shared__ unsigned short Asl[2][128 * 64];
    __shared__ unsigned short Bsl[2][128 * 64];
    const int tid = threadIdx.x;
    const int wv = tid >> 6, l = tid & 63;
    const int wm = wv >> 1, wn = wv & 1;
    const int lg = l >> 4, l15 = l & 15;
    const int m0 = blockIdx.x * 128, n0 = blockIdx.y * 128;

    // staging source pointers (pre-swizzled column), advance +64 per K-tile
    const unsigned short* asrc[4];
    const unsigned short* bsrc[4];
#pragma unroll
    for (int i = 0; i < 4; i++) {
        int c = (wv * 4 + i) * 64 + l;
        int r = c >> 3, kc = c & 7;
        int sc = (kc ^ (r & 7)) * 8;
        asrc[i] = A + (size_t)(m0 + r) * CC + sc;
        bsrc[i] = Bw + (size_t)(n0 + r) * CC + sc;
    }

#define QSTAGE(buf) do { \
    _Pragma("unroll") \
    for (int i = 0; i < 4; i++) { \
        __builtin_amdgcn_global_load_lds((AS1 void*)asrc[i], (AS3 void*)(&Asl[buf][(wv * 4 + i) * 512]), 16, 0, 0); \
        __builtin_amdgcn_global_load_lds((AS1 void*)bsrc[i], (AS3 void*)(&Bsl[buf][(wv * 4 + i) * 512]), 16, 0, 0); \
        asrc[i] += 64; bsrc[i] += 64; \
    } \
} while (0)

#define QCOMPUTE(buf) do { \
    _Pragma("unroll") \
    for (int kc = 0; kc < 2; kc++) { \
        bf16x8 af[4], bfr[4]; \
        _Pragma("unroll") \
        for (int mi = 0; mi < 4; mi++) { \
            int r = wm * 64 + mi * 16 + l15; \
            af[mi] = *(const bf16x8*)(&Asl[buf][r * 64 + (((kc * 4 + lg) ^ (r & 7)) * 8)]); \
        } \
        _Pragma("unroll") \
        for (int nj = 0; nj < 4; nj++) { \
            int r = wn * 64 + nj * 16 + l15; \
            bfr[nj] = *(const bf16x8*)(&Bsl[buf][r * 64 + (((kc * 4 + lg) ^ (r & 7)) * 8)]); \
        } \
        _Pragma("unroll") \
        for (int mi = 0; mi < 4; mi++) \
            _Pragma("unroll") \
            for (int nj = 0; nj < 4; nj++) \
                acc[mi][nj] = __builtin_amdgcn_mfma_f32_16x16x32_bf16(af[mi], bfr[nj], acc[mi][nj], 0, 0, 0); \
    } \
} while (0)

#define QSYNC_PRE() do { \
    asm volatile("s_waitcnt vmcnt(8)" ::: "memory"); \
    __builtin_amdgcn_sched_barrier(0); \
    __builtin_amdgcn_s_barrier(); \
    __builtin_amdgcn_sched_barrier(0); \
} while (0)

#define QSYNC_POST() do { \
    __builtin_amdgcn_sched_barrier(0); \
    __builtin_amdgcn_s_barrier(); \
} while (0)

    f32x4 acc[4][4];
#pragma unroll
    for (int i = 0; i < 4; i++)
#pragma unroll
        for (int j = 0; j < 4; j++) acc[i][j] = f32x4{0.f, 0.f, 0.f, 0.f};

    QSTAGE(0);                       // tile 0 -> buf0
    for (int ktb = 0; ktb < 16; ktb += 2) {
        // even iter: prefetch next tile -> buf1, compute buf0
        QSTAGE(1);                   // tile ktb+1 (ktb=14 -> tile 15)
        QSYNC_PRE();
        QCOMPUTE(0);
        QSYNC_POST();
        // odd iter: prefetch -> buf0 (last iteration stages a harmless dummy)
        QSTAGE(0);                   // tile ktb+2 (ktb=14 -> dummy past-end, never read)
        QSYNC_PRE();
        QCOMPUTE(1);
        QSYNC_POST();
    }

    // epilogue: RoPE for q/k ([bh][n][d]); v transposed ([bh][d][n])
    const int b_ = m0 >> 11;
    const int nrow0 = (m0 & (NN - 1));
#pragma unroll
    for (int nj = 0; nj < 4; nj++) {
        int oc = n0 + wn * 64 + nj * 16 + l15;
        int s = oc >> 10;
        int rr = oc & 1023;
        int h = rr >> 6;
        int d = rr & 63;
        int f = d >> 1;
#pragma unroll
        for (int mi = 0; mi < 4; mi++) {
            f32x4 v = acc[mi][nj];
            if (s == 2) {
                u16x4 vv;
#pragma unroll
                for (int reg = 0; reg < 4; reg++) vv[reg] = f2bf(v[reg]);
                int nb = nrow0 + wm * 64 + mi * 16 + lg * 4;
                *(u16x4*)(vbT + ((size_t)((b_ * HH + h) * HD + d)) * NN + nb) = vv;
            } else {
#pragma unroll
                for (int reg = 0; reg < 4; reg++) {
                    int m = m0 + wm * 64 + mi * 16 + lg * 4 + reg;
                    int n = m & (NN - 1);
                    float val = v[reg];
                    float partner = __shfl_xor(val, 1);
                    size_t base = (((size_t)(b_ * HH + h)) * NN + n) * HD + d;
                    float2 cs2 = *(const float2*)(csT + 2 * ((size_t)n * NF + h * HALF + f));
                    float res = ((d & 1) == 0) ? (val * cs2.x - partner * cs2.y)
                                               : (val * cs2.x + partner * cs2.y);
                    if (s == 0) res *= 0.18033688011112043f;  // 0.125 * log2(e)
                    (s == 0 ? qb : kb)[base] = f2bf(res);
                }
            }
        }
    }
#undef QSTAGE
#undef QCOMPUTE
#undef QSYNC_PRE
#undef QSYNC_POST
}

// ---------------- kernel 5: flash attention (verified round-7 version, exact) ----------------
template<int BUF>
__device__ __forceinline__ void attn_iter(
    unsigned short* LB, bool do_stage, int wv, int l31,
    const unsigned short*& kn0, const unsigned short*& kn1,
    const unsigned short*& vn0, const unsigned short*& vn1,
    const int (&so)[4], const bf16x8 (&qfA)[4], const bf16x8 (&qfB)[4],
    const f32x16& Z, const bf16x8& ones,
    f32x16& OA0, f32x16& OA1, f32x16& OB0, f32x16& OB1,
    f32x16& SsA, f32x16& SsB) {
    if (do_stage) {
        const int nb = (BUF ^ 1) * 4096;
        __builtin_amdgcn_global_load_lds((AS1 void*)kn0, (AS3 void*)(&LB[nb + (wv * 2 + 0) * 512]), 16, 0, 0);
        __builtin_amdgcn_global_load_lds((AS1 void*)kn1, (AS3 void*)(&LB[nb + (wv * 2 + 1) * 512]), 16, 0, 0);
        __builtin_amdgcn_global_load_lds((AS1 void*)vn0, (AS3 void*)(&LB[8192 + nb + (wv * 2 + 0) * 512]), 16, 0, 0);
        __builtin_amdgcn_global_load_lds((AS1 void*)vn1, (AS3 void*)(&LB[8192 + nb + (wv * 2 + 1) * 512]), 16, 0, 0);
        kn0 += 4096; kn1 += 4096; vn0 += 64; vn1 += 64;
    }
    f32x16 sA0, sA1, sB0, sB1;
    __builtin_amdgcn_s_setprio(1);
    {
        bf16x8 a0 = *(const bf16x8*)(LB + BUF * 4096 + l31 * 64 + so[0]);
        bf16x8 a1 = *(const bf16x8*)(LB + BUF * 4096 + (32 + l31) * 64 + so[0]);
        sA0 = __builtin_amdgcn_mfma_f32_32x32x16_bf16(a0, qfA[0], Z, 0, 0, 0);
        sA1 = __builtin_amdgcn_mfma_f32_32x32x16_bf16(a1, qfA[0], Z, 0, 0, 0);
        sB0 = __builtin_amdgcn_mfma_f32_32x32x16_bf16(a0, qfB[0], Z, 0, 0, 0);
        sB1 = __builtin_amdgcn_mfma_f32_32x32x16_bf16(a1, qfB[0], Z, 0, 0, 0);
    }
#pragma unroll
    for (int dc = 1; dc < 4; dc++) {
        bf16x8 a0 = *(const bf16x8*)(LB + BUF * 4096 + l31 * 64 + so[dc]);
        bf16x8 a1 = *(const bf16x8*)(LB + BUF * 4096 + (32 + l31) * 64 + so[dc]);
        sA0 = __builtin_amdgcn_mfma_f32_32x32x16_bf16(a0, qfA[dc], sA0, 0, 0, 0);
        sA1 = __builtin_amdgcn_mfma_f32_32x32x16_bf16(a1, qfA[dc], sA1, 0, 0, 0);
        sB0 = __builtin_amdgcn_mfma_f32_32x32x16_bf16(a0, qfB[dc], sB0, 0, 0, 0);
        sB1 = __builtin_amdgcn_mfma_f32_32x32x16_bf16(a1, qfB[dc], sB1, 0, 0, 0);
    }
    __builtin_amdgcn_s_setprio(0);
#pragma unroll
    for (int r = 0; r < 16; r++) {
        sA0[r] = EXP2(sA0[r]); sA1[r] = EXP2(sA1[r]);
        sB0[r] = EXP2(sB0[r]); sB1[r] = EXP2(sB1[r]);
    }
#pragma unroll
    for (int r = 0; r < 8; r++) {
        unsigned u0, u1, u2, u3;
        asm("v_cvt_pk_bf16_f32 %0, %1, %2" : "=v"(u0) : "v"(sA0[2 * r]), "v"(sA0[2 * r + 1]));
        asm("v_cvt_pk_bf16_f32 %0, %1, %2" : "=v"(u1) : "v"(sA1[2 * r]), "v"(sA1[2 * r + 1]));
        asm("v_cvt_pk_bf16_f32 %0, %1, %2" : "=v"(u2) : "v"(sB0[2 * r]), "v"(sB0[2 * r + 1]));
        asm("v_cvt_pk_bf16_f32 %0, %1, %2" : "=v"(u3) : "v"(sB1[2 * r]), "v"(sB1[2 * r + 1]));
        sA0[2 * r] = __uint_as_float(u0);
        sA1[2 * r] = __uint_as_float(u1);
        sB0[2 * r] = __uint_as_float(u2);
        sB1[2 * r] = __uint_as_float(u3);
    }
    __builtin_amdgcn_s_setprio(1);
#pragma unroll
    for (int kc = 0; kc < 4; kc++) {
        const int bs = (kc & 1) * 8;
        bf16x8 pfA, pfB;
        {
            float e0 = (kc < 2) ? sA0[bs + 0] : sA1[bs + 0];
            float e4 = (kc < 2) ? sA0[bs + 4] : sA1[bs + 4];
            float e2 = (kc < 2) ? sA0[bs + 2] : sA1[bs + 2];
            float e6 = (kc < 2) ? sA0[bs + 6] : sA1[bs + 6];
            auto uA = __builtin_amdgcn_permlane32_swap(__float_as_uint(e0), __float_as_uint(e4), false, false);
            auto uB = __builtin_amdgcn_permlane32_swap(__float_as_uint(e2), __float_as_uint(e6), false, false);
            u32x4 t; t.x = uA[0]; t.y = uB[0]; t.z = uA[1]; t.w = uB[1];
            pfA = __builtin_bit_cast(bf16x8, t);
        }
        {
            float e0 = (kc < 2) ? sB0[bs + 0] : sB1[bs + 0];
            float e4 = (kc < 2) ? sB0[bs + 4] : sB1[bs + 4];
            float e2 = (kc < 2) ? sB0[bs + 2] : sB1[bs + 2];
            float e6 = (kc < 2) ? sB0[bs + 6] : sB1[bs + 6];
            auto uA = __builtin_amdgcn_permlane32_swap(__float_as_uint(e0), __float_as_uint(e4), false, false);
            auto uB = __builtin_amdgcn_permlane32_swap(__float_as_uint(e2), __float_as_uint(e6), false, false);
            u32x4 t; t.x = uA[0]; t.y = uB[0]; t.z = uA[1]; t.w = uB[1];
            pfB = __builtin_bit_cast(bf16x8, t);
        }
        bf16x8 va  = *(const bf16x8*)(LB + 8192 + BUF * 4096 + l31 * 64 + so[kc]);
        bf16x8 vb2 = *(const bf16x8*)(LB + 8192 + BUF * 4096 + (32 + l31) * 64 + so[kc]);
        OA0 = __builtin_amdgcn_mfma_f32_32x32x16_bf16(va,  pfA, OA0, 0, 0, 0);
        OA1 = __builtin_amdgcn_mfma_f32_32x32x16_bf16(vb2, pfA, OA1, 0, 0, 0);
        OB0 = __builtin_amdgcn_mfma_f32_32x32x16_bf16(va,  pfB, OB0, 0, 0, 0);
        OB1 = __builtin_amdgcn_mfma_f32_32x32x16_bf16(vb2, pfB, OB1, 0, 0, 0);
        SsA = __builtin_amdgcn_mfma_f32_32x32x16_bf16(ones, pfA, SsA, 0, 0, 0);
        SsB = __builtin_amdgcn_mfma_f32_32x32x16_bf16(ones, pfB, SsB, 0, 0, 0);
    }
    __builtin_amdgcn_s_setprio(0);
    __syncthreads();
}

__global__ __launch_bounds__(256, 2) void attn_mfma_kernel(const unsigned short* __restrict__ qbp,
                                                           const unsigned short* __restrict__ kbp,
                                                           const unsigned short* __restrict__ vtp,
                                                           unsigned short* __restrict__ aout) {
    __shared__ unsigned short LB[4 * 4096];      // K0,K1,V0,V1
    const int tid = threadIdx.x;
    const int wv = tid >> 6;       // 0..3
    const int l = tid & 63;
    const int l31 = l & 31, hi = l >> 5;

    const int wg = blockIdx.x;                    // 0..511
    const int Lidx = (wg & 7) * 64 + (wg >> 3);
    const int bh = Lidx >> 3;
    const int q0 = (Lidx & 7) * 256;

    const unsigned short* qp = qbp + (size_t)bh * (NN * HD);
    const unsigned short* kp = kbp + (size_t)bh * (NN * HD);
    const unsigned short* vp = vtp + (size_t)bh * (NN * HD);

    const int r0 = (wv * 2 + 0) * 8 + (l >> 3);
    const int r1 = (wv * 2 + 1) * 8 + (l >> 3);
    const int c0 = ((l & 7) ^ (r0 & 7)) * 8;
    const int c1 = ((l & 7) ^ (r1 & 7)) * 8;
    const unsigned short* kn0 = kp + r0 * HD + c0;
    const unsigned short* kn1 = kp + r1 * HD + c1;
    const unsigned short* vn0 = vp + (size_t)r0 * NN + c0;
    const unsigned short* vn1 = vp + (size_t)r1 * NN + c1;

    __builtin_amdgcn_global_load_lds((AS1 void*)kn0, (AS3 void*)(&LB[(wv * 2 + 0) * 512]), 16, 0, 0);
    __builtin_amdgcn_global_load_lds((AS1 void*)kn1, (AS3 void*)(&LB[(wv * 2 + 1) * 512]), 16, 0, 0);
    __builtin_amdgcn_global_load_lds((AS1 void*)vn0, (AS3 void*)(&LB[8192 + (wv * 2 + 0) * 512]), 16, 0, 0);
    __builtin_amdgcn_global_load_lds((AS1 void*)vn1, (AS3 void*)(&LB[8192 + (wv * 2 + 1) * 512]), 16, 0, 0);
    kn0 += 4096; kn1 += 4096; vn0 += 64; vn1 += 64;

    const unsigned short* qr = qp + (size_t)(q0 + wv * 64 + l31) * HD;
    bf16x8 qfA[4], qfB[4];
#pragma unroll
    for (int dc = 0; dc < 4; dc++) {
        qfA[dc] = *(const bf16x8*)(qr + dc * 16 + hi * 8);
        qfB[dc] = *(const bf16x8*)(qr + 32 * HD + dc * 16 + hi * 8);
    }

    int so[4];
#pragma unroll
    for (int i = 0; i < 4; i++) so[i] = ((2 * i + hi) ^ (l31 & 7)) * 8;

    f32x16 Z;
#pragma unroll
    for (int r = 0; r < 16; r++) Z[r] = 0.0f;
    f32x16 OA0 = Z, OA1 = Z, OB0 = Z, OB1 = Z, SsA = Z, SsB = Z;
    bf16x8 ones;
#pragma unroll
    for (int j = 0; j < 8; j++) ones[j] = (short)0x3F80;  // bf16 1.0

    __syncthreads();

    for (int ktb = 0; ktb < NT; ktb += 2) {
        attn_iter<0>(LB, true, wv, l31, kn0, kn1, vn0, vn1, so, qfA, qfB,
                     Z, ones, OA0, OA1, OB0, OB1, SsA, SsB);
        attn_iter<1>(LB, ktb + 2 < NT, wv, l31, kn0, kn1, vn0, vn1, so, qfA, qfB,
                     Z, ones, OA0, OA1, OB0, OB1, SsA, SsB);
    }

    const int b_ = bh >> 4, hh = bh & 15;
    const float invA = 1.0f / SsA[0], invB = 1.0f / SsB[0];
    const size_t mrowA = (size_t)(b_ * NN + q0 + wv * 64 + l31) * CC + hh * HD;
    const size_t mrowB = mrowA + (size_t)32 * CC;
#pragma unroll
    for (int rq = 0; rq < 4; rq++) {
        u16x4 a0, a1, b0, b1;
#pragma unroll
        for (int j = 0; j < 4; j++) {
            a0[j] = f2bf(OA0[rq * 4 + j] * invA);
            a1[j] = f2bf(OA1[rq * 4 + j] * invA);
            b0[j] = f2bf(OB0[rq * 4 + j] * invB);
            b1[j] = f2bf(OB1[rq * 4 + j] * invB);
        }
        *(u16x4*)(aout + mrowA + rq * 8 + hi * 4) = a0;
        *(u16x4*)(aout + mrowA + 32 + rq * 8 + hi * 4) = a1;
        *(u16x4*)(aout + mrowB + rq * 8 + hi * 4) = b0;
        *(u16x4*)(aout + mrowB + 32 + rq * 8 + hi * 4) = b1;
    }
}

// ---------------- kernel 6: proj GEMM (bf16 MFMA) + bias (2D grid) ----------------
__global__ __launch_bounds__(256) void proj_gemm_kernel(const unsigned short* __restrict__ A,
                                                        const unsigned short* __restrict__ Bw,
                                                        const float* __restrict__ bp,
                                                        float* __restrict__ out) {
    __shared__ unsigned short Asl[128 * 64];
    __shared__ unsigned short Bsl[128 * 64];
    const int tid = threadIdx.x;
    const int wv = tid >> 6, l = tid & 63;
    const int wm = wv >> 1, wn = wv & 1;
    const int lg = l >> 4, l15 = l & 15;
    const int m0 = blockIdx.x * 128, n0 = blockIdx.y * 128;

    f32x4 acc[4][4];
#pragma unroll
    for (int i = 0; i < 4; i++)
#pragma unroll
        for (int j = 0; j < 4; j++) acc[i][j] = f32x4{0.f, 0.f, 0.f, 0.f};

    for (int kt = 0; kt < CC; kt += 64) {
        __syncthreads();
#pragma unroll
        for (int i = 0; i < 4; i++) {
            int c = (wv * 4 + i) * 64 + l;
            int r = c >> 3, kc = c & 7;
            int sc = kt + ((kc ^ (r & 7)) * 8);
            __builtin_amdgcn_global_load_lds(
                (AS1 void*)(A + (size_t)(m0 + r) * CC + sc),
                (AS3 void*)(&Asl[(wv * 4 + i) * 512]), 16, 0, 0);
            __builtin_amdgcn_global_load_lds(
                (AS1 void*)(Bw + (size_t)(n0 + r) * CC + sc),
                (AS3 void*)(&Bsl[(wv * 4 + i) * 512]), 16, 0, 0);
        }
        __syncthreads();
#pragma unroll
        for (int kc = 0; kc < 2; kc++) {
            bf16x8 af[4], bfr[4];
#pragma unroll
            for (int mi = 0; mi < 4; mi++) {
                int r = wm * 64 + mi * 16 + l15;
                af[mi] = *(const bf16x8*)(&Asl[r * 64 + (((kc * 4 + lg) ^ (r & 7)) * 8)]);
            }
#pragma unroll
            for (int nj = 0; nj < 4; nj++) {
                int r = wn * 64 + nj * 16 + l15;
                bfr[nj] = *(const bf16x8*)(&Bsl[r * 64 + (((kc * 4 + lg) ^ (r & 7)) * 8)]);
            }
#pragma unroll
            for (int mi = 0; mi < 4; mi++)
#pragma unroll
                for (int nj = 0; nj < 4; nj++)
                    acc[mi][nj] = __builtin_amdgcn_mfma_f32_16x16x32_bf16(af[mi], bfr[nj], acc[mi][nj], 0, 0, 0);
        }
    }
    float bias[4];
#pragma unroll
    for (int nj = 0; nj < 4; nj++) bias[nj] = bp[n0 + wn * 64 + nj * 16 + l15];
#pragma unroll
    for (int mi = 0; mi < 4; mi++)
#pragma unroll
        for (int nj = 0; nj < 4; nj++) {
            int oc = n0 + wn * 64 + nj * 16 + l15;
#pragma unroll
            for (int reg = 0; reg < 4; reg++) {
                int m = m0 + wm * 64 + mi * 16 + lg * 4 + reg;
                out[(size_t)m * CC + oc] = acc[mi][nj][reg] + bias[nj];
            }
        }
}

extern "C" void kernel_launch(void* const* d_in, const int* in_sizes, int n_in,
                              void* d_out, int out_size, void* d_ws, size_t ws_size,
                              hipStream_t stream) {
    const float* x      = (const float*)d_in[0];
    const float* t_x    = (const float*)d_in[1];
    const float* t_y    = (const float*)d_in[2];
    const float* t_z    = (const float*)d_in[3];
    const float* w_qkv  = (const float*)d_in[4];
    const float* w_proj = (const float*)d_in[5];
    const float* b_proj = (const float*)d_in[6];
    const float* freqs  = (const float*)d_in[7];
    float* out = (float*)d_out;

    unsigned short* xb     = (unsigned short*)d_ws;            // MM*CC
    unsigned short* wqkvb  = xb + (size_t)MM * CC;             // K3*CC
    unsigned short* wprojb = wqkvb + (size_t)K3 * CC;          // CC*CC
    unsigned short* qbuf   = wprojb + (size_t)CC * CC;         // B*H*N*HD
    unsigned short* kbuf   = qbuf + (size_t)BB * HH * NN * HD;
    unsigned short* vbT    = kbuf + (size_t)BB * HH * NN * HD; // [bh][d][n]
    unsigned short* attnb  = vbT + (size_t)BB * HH * NN * HD;
    float* csT   = (float*)(attnb + (size_t)MM * CC);          // NN*NF float2
    float* tnorm = csT + (size_t)2 * NN * NF;

    tnorm_kernel<<<3, 256, 0, stream>>>(t_x, t_y, t_z, tnorm);
    angle_kernel<<<NN, 512, 0, stream>>>(freqs, tnorm, csT);
    cvt_all_kernel<<<XBLK + WQBLK + WPBLK, 256, 0, stream>>>(x, w_qkv, w_proj,
                                                             xb, wqkvb, wprojb);
    qkv_gemm_kernel<<<dim3(MM / 128, K3 / 128), 256, 0, stream>>>(xb, wqkvb, csT,
                                                                  qbuf, kbuf, vbT);
    attn_mfma_kernel<<<512, 256, 0, stream>>>(qbuf, kbuf, vbT, attnb);
    proj_gemm_kernel<<<dim3(MM / 128, CC / 128), 256, 0, stream>>>(attnb, wprojb, b_proj, out);
}

// Round 15
// 198.148 us; speedup vs baseline: 1.1638x; 1.0087x over previous
//
#include <hip/hip_runtime.h>
#include <math.h>

#define BB 4
#define NN 2048
#define CC 1024
#define HH 16
#define HD 64
#define HALF 32
#define MM (BB*NN)     // 8192
#define K3 (3*CC)      // 3072
#define NF (HH*HALF)   // 512
#define NT (NN/64)     // 32 k-tiles (attn)

typedef __attribute__((ext_vector_type(8))) short bf16x8;
typedef __attribute__((ext_vector_type(4))) float f32x4;
typedef __attribute__((ext_vector_type(16))) float f32x16;
typedef __attribute__((ext_vector_type(4))) unsigned short u16x4;
typedef __attribute__((ext_vector_type(8))) unsigned short u16x8;
typedef __attribute__((ext_vector_type(4))) unsigned int u32x4;

#if __has_builtin(__builtin_amdgcn_exp2f)
#define EXP2(x) __builtin_amdgcn_exp2f(x)
#else
#define EXP2(x) exp2f(x)
#endif
#define AS1 __attribute__((address_space(1)))
#define AS3 __attribute__((address_space(3)))

__device__ __forceinline__ unsigned short f2bf(float f) {
    unsigned int u = __float_as_uint(f);
    unsigned int r = (u + 0x7FFFu + ((u >> 16) & 1u)) >> 16;
    return (unsigned short)r;
}

// ---------------- kernel 1: normalize t arrays ----------------
__global__ __launch_bounds__(256) void tnorm_kernel(const float* t_x, const float* t_y,
                                                    const float* t_z, float* tnorm) {
    int a = blockIdx.x;
    const float* t = (a == 0) ? t_x : ((a == 1) ? t_y : t_z);
    __shared__ float smn[256], smx[256];
    float mn = 1e30f, mx = -1e30f;
    for (int i = threadIdx.x; i < NN; i += 256) {
        float v = t[i];
        mn = fminf(mn, v);
        mx = fmaxf(mx, v);
    }
    smn[threadIdx.x] = mn; smx[threadIdx.x] = mx;
    __syncthreads();
    for (int s = 128; s > 0; s >>= 1) {
        if (threadIdx.x < s) {
            smn[threadIdx.x] = fminf(smn[threadIdx.x], smn[threadIdx.x + s]);
            smx[threadIdx.x] = fmaxf(smx[threadIdx.x], smx[threadIdx.x + s]);
        }
        __syncthreads();
    }
    float lo = smn[0];
    float sc = 32.0f / (smx[0] - lo + 1e-8f);
    for (int i = threadIdx.x; i < NN; i += 256)
        tnorm[a * NN + i] = (t[i] - lo) * sc;
}

// ---------------- kernel 2: angle -> interleaved {cos,sin} table (float2) ----------------
__global__ __launch_bounds__(512) void angle_kernel(const float* freqs, const float* tnorm,
                                                    float* csT) {
    int n = blockIdx.x;
    int hf = threadIdx.x;  // 0..511
    float ang = tnorm[n] * freqs[hf]
              + tnorm[NN + n] * freqs[NF + hf]
              + tnorm[2 * NN + n] * freqs[2 * NF + hf];
    float2 cs;
    cs.x = cosf(ang);
    cs.y = sinf(ang);
    *(float2*)(csT + 2 * ((size_t)n * NF + hf)) = cs;
}

// ---------------- kernel 3: fused f32 -> bf16 convert for x, w_qkv, w_proj ----------------
#define XBLK (MM * CC / 2048)          // 4096
#define WQBLK (K3 * CC / 2048)         // 1536
#define WPBLK (CC * CC / 2048)         // 512
__global__ __launch_bounds__(256) void cvt_all_kernel(const float* __restrict__ x,
                                                      const float* __restrict__ wq,
                                                      const float* __restrict__ wp,
                                                      unsigned short* __restrict__ xb,
                                                      unsigned short* __restrict__ wqb,
                                                      unsigned short* __restrict__ wpb) {
    int bid = blockIdx.x;
    const float* src;
    unsigned short* dst;
    if (bid < XBLK) { src = x; dst = xb; }
    else if (bid < XBLK + WQBLK) { src = wq; dst = wqb; bid -= XBLK; }
    else { src = wp; dst = wpb; bid -= XBLK + WQBLK; }
    int i = (bid * 256 + threadIdx.x) * 8;
    float4 a = *(const float4*)(src + i);
    float4 b = *(const float4*)(src + i + 4);
    u16x8 o;
    o[0] = f2bf(a.x); o[1] = f2bf(a.y); o[2] = f2bf(a.z); o[3] = f2bf(a.w);
    o[4] = f2bf(b.x); o[5] = f2bf(b.y); o[6] = f2bf(b.z); o[7] = f2bf(b.w);
    *(u16x8*)(dst + i) = o;
}

// ---- shared GEMM pipeline macros (dbuf + counted vmcnt, verified r14) ----
#define GSTAGE(Abuf, Bbuf, buf) do { \
    _Pragma("unroll") \
    for (int i = 0; i < 4; i++) { \
        __builtin_amdgcn_global_load_lds((AS1 void*)asrc[i], (AS3 void*)(&Abuf[buf][(wv * 4 + i) * 512]), 16, 0, 0); \
        __builtin_amdgcn_global_load_lds((AS1 void*)bsrc[i], (AS3 void*)(&Bbuf[buf][(wv * 4 + i) * 512]), 16, 0, 0); \
        asrc[i] += 64; bsrc[i] += 64; \
    } \
} while (0)

#define GCOMPUTE(Abuf, Bbuf, buf) do { \
    _Pragma("unroll") \
    for (int kc = 0; kc < 2; kc++) { \
        bf16x8 af[4], bfr[4]; \
        _Pragma("unroll") \
        for (int mi = 0; mi < 4; mi++) { \
            int r = wm * 64 + mi * 16 + l15; \
            af[mi] = *(const bf16x8*)(&Abuf[buf][r * 64 + (((kc * 4 + lg) ^ (r & 7)) * 8)]); \
        } \
        _Pragma("unroll") \
        for (int nj = 0; nj < 4; nj++) { \
            int r = wn * 64 + nj * 16 + l15; \
            bfr[nj] = *(const bf16x8*)(&Bbuf[buf][r * 64 + (((kc * 4 + lg) ^ (r & 7)) * 8)]); \
        } \
        _Pragma("unroll") \
        for (int mi = 0; mi < 4; mi++) \
            _Pragma("unroll") \
            for (int nj = 0; nj < 4; nj++) \
                acc[mi][nj] = __builtin_amdgcn_mfma_f32_16x16x32_bf16(af[mi], bfr[nj], acc[mi][nj], 0, 0, 0); \
    } \
} while (0)

#define GSYNC_PRE() do { \
    asm volatile("s_waitcnt vmcnt(8)" ::: "memory"); \
    __builtin_amdgcn_sched_barrier(0); \
    __builtin_amdgcn_s_barrier(); \
    __builtin_amdgcn_sched_barrier(0); \
} while (0)

#define GSYNC_POST() do { \
    __builtin_amdgcn_sched_barrier(0); \
    __builtin_amdgcn_s_barrier(); \
} while (0)

// ---------------- kernel 4: QKV GEMM, dbuf + counted vmcnt pipeline + fused RoPE ----------------
__global__ __launch_bounds__(256) void qkv_gemm_kernel(const unsigned short* __restrict__ A,
                                                       const unsigned short* __restrict__ Bw,
                                                       const float* __restrict__ csT,
                                                       unsigned short* __restrict__ qb,
                                                       unsigned short* __restrict__ kb,
                                                       unsigned short* __restrict__ vbT) {
    __shared__ unsigned short Asl[2][128 * 64];
    __shared__ unsigned short Bsl[2][128 * 64];
    const int tid = threadIdx.x;
    const int wv = tid >> 6, l = tid & 63;
    const int wm = wv >> 1, wn = wv & 1;
    const int lg = l >> 4, l15 = l & 15;
    const int m0 = blockIdx.x * 128, n0 = blockIdx.y * 128;

    const unsigned short* asrc[4];
    const unsigned short* bsrc[4];
#pragma unroll
    for (int i = 0; i < 4; i++) {
        int c = (wv * 4 + i) * 64 + l;
        int r = c >> 3, kc = c & 7;
        int sc = (kc ^ (r & 7)) * 8;
        asrc[i] = A + (size_t)(m0 + r) * CC + sc;
        bsrc[i] = Bw + (size_t)(n0 + r) * CC + sc;
    }

    f32x4 acc[4][4];
#pragma unroll
    for (int i = 0; i < 4; i++)
#pragma unroll
        for (int j = 0; j < 4; j++) acc[i][j] = f32x4{0.f, 0.f, 0.f, 0.f};

    GSTAGE(Asl, Bsl, 0);
    for (int ktb = 0; ktb < 16; ktb += 2) {
        GSTAGE(Asl, Bsl, 1);
        GSYNC_PRE();
        GCOMPUTE(Asl, Bsl, 0);
        GSYNC_POST();
        GSTAGE(Asl, Bsl, 0);     // tail iteration stages a harmless dummy
        GSYNC_PRE();
        GCOMPUTE(Asl, Bsl, 1);
        GSYNC_POST();
    }

    // epilogue: RoPE for q/k ([bh][n][d]); v transposed ([bh][d][n])
    const int b_ = m0 >> 11;
    const int nrow0 = (m0 & (NN - 1));
#pragma unroll
    for (int nj = 0; nj < 4; nj++) {
        int oc = n0 + wn * 64 + nj * 16 + l15;
        int s = oc >> 10;
        int rr = oc & 1023;
        int h = rr >> 6;
        int d = rr & 63;
        int f = d >> 1;
#pragma unroll
        for (int mi = 0; mi < 4; mi++) {
            f32x4 v = acc[mi][nj];
            if (s == 2) {
                u16x4 vv;
#pragma unroll
                for (int reg = 0; reg < 4; reg++) vv[reg] = f2bf(v[reg]);
                int nb = nrow0 + wm * 64 + mi * 16 + lg * 4;
                *(u16x4*)(vbT + ((size_t)((b_ * HH + h) * HD + d)) * NN + nb) = vv;
            } else {
#pragma unroll
                for (int reg = 0; reg < 4; reg++) {
                    int m = m0 + wm * 64 + mi * 16 + lg * 4 + reg;
                    int n = m & (NN - 1);
                    float val = v[reg];
                    float partner = __shfl_xor(val, 1);
                    size_t base = (((size_t)(b_ * HH + h)) * NN + n) * HD + d;
                    float2 cs2 = *(const float2*)(csT + 2 * ((size_t)n * NF + h * HALF + f));
                    float res = ((d & 1) == 0) ? (val * cs2.x - partner * cs2.y)
                                               : (val * cs2.x + partner * cs2.y);
                    if (s == 0) res *= 0.18033688011112043f;  // 0.125 * log2(e)
                    (s == 0 ? qb : kb)[base] = f2bf(res);
                }
            }
        }
    }
}

// ---------------- kernel 5: flash attention, counted-vmcnt pipeline ----------------
// r7-verified math; __syncthreads replaced by vmcnt(4)+s_barrier / raw s_barrier (qkv-proven
// pattern). Always-stage keeps the count uniform; tail dummy loads stay in workspace.
template<int BUF>
__device__ __forceinline__ void attn_iter(
    unsigned short* LB, int wv, int l31,
    const unsigned short*& kn0, const unsigned short*& kn1,
    const unsigned short*& vn0, const unsigned short*& vn1,
    const int (&so)[4], const bf16x8 (&qfA)[4], const bf16x8 (&qfB)[4],
    const f32x16& Z, const bf16x8& ones,
    f32x16& OA0, f32x16& OA1, f32x16& OB0, f32x16& OB1,
    f32x16& SsA, f32x16& SsB) {
    {
        const int nb = (BUF ^ 1) * 4096;
        __builtin_amdgcn_global_load_lds((AS1 void*)kn0, (AS3 void*)(&LB[nb + (wv * 2 + 0) * 512]), 16, 0, 0);
        __builtin_amdgcn_global_load_lds((AS1 void*)kn1, (AS3 void*)(&LB[nb + (wv * 2 + 1) * 512]), 16, 0, 0);
        __builtin_amdgcn_global_load_lds((AS1 void*)vn0, (AS3 void*)(&LB[8192 + nb + (wv * 2 + 0) * 512]), 16, 0, 0);
        __builtin_amdgcn_global_load_lds((AS1 void*)vn1, (AS3 void*)(&LB[8192 + nb + (wv * 2 + 1) * 512]), 16, 0, 0);
        kn0 += 4096; kn1 += 4096; vn0 += 64; vn1 += 64;
    }
    // wait: this wave's PREVIOUS-tile loads (to buf BUF) done; the 4 new stay in flight
    asm volatile("s_waitcnt vmcnt(4)" ::: "memory");
    __builtin_amdgcn_sched_barrier(0);
    __builtin_amdgcn_s_barrier();
    __builtin_amdgcn_sched_barrier(0);

    f32x16 sA0, sA1, sB0, sB1;
    __builtin_amdgcn_s_setprio(1);
    {
        bf16x8 a0 = *(const bf16x8*)(LB + BUF * 4096 + l31 * 64 + so[0]);
        bf16x8 a1 = *(const bf16x8*)(LB + BUF * 4096 + (32 + l31) * 64 + so[0]);
        sA0 = __builtin_amdgcn_mfma_f32_32x32x16_bf16(a0, qfA[0], Z, 0, 0, 0);
        sA1 = __builtin_amdgcn_mfma_f32_32x32x16_bf16(a1, qfA[0], Z, 0, 0, 0);
        sB0 = __builtin_amdgcn_mfma_f32_32x32x16_bf16(a0, qfB[0], Z, 0, 0, 0);
        sB1 = __builtin_amdgcn_mfma_f32_32x32x16_bf16(a1, qfB[0], Z, 0, 0, 0);
    }
#pragma unroll
    for (int dc = 1; dc < 4; dc++) {
        bf16x8 a0 = *(const bf16x8*)(LB + BUF * 4096 + l31 * 64 + so[dc]);
        bf16x8 a1 = *(const bf16x8*)(LB + BUF * 4096 + (32 + l31) * 64 + so[dc]);
        sA0 = __builtin_amdgcn_mfma_f32_32x32x16_bf16(a0, qfA[dc], sA0, 0, 0, 0);
        sA1 = __builtin_amdgcn_mfma_f32_32x32x16_bf16(a1, qfA[dc], sA1, 0, 0, 0);
        sB0 = __builtin_amdgcn_mfma_f32_32x32x16_bf16(a0, qfB[dc], sB0, 0, 0, 0);
        sB1 = __builtin_amdgcn_mfma_f32_32x32x16_bf16(a1, qfB[dc], sB1, 0, 0, 0);
    }
    __builtin_amdgcn_s_setprio(0);
#pragma unroll
    for (int r = 0; r < 16; r++) {
        sA0[r] = EXP2(sA0[r]); sA1[r] = EXP2(sA1[r]);
        sB0[r] = EXP2(sB0[r]); sB1[r] = EXP2(sB1[r]);
    }
#pragma unroll
    for (int r = 0; r < 8; r++) {
        unsigned u0, u1, u2, u3;
        asm("v_cvt_pk_bf16_f32 %0, %1, %2" : "=v"(u0) : "v"(sA0[2 * r]), "v"(sA0[2 * r + 1]));
        asm("v_cvt_pk_bf16_f32 %0, %1, %2" : "=v"(u1) : "v"(sA1[2 * r]), "v"(sA1[2 * r + 1]));
        asm("v_cvt_pk_bf16_f32 %0, %1, %2" : "=v"(u2) : "v"(sB0[2 * r]), "v"(sB0[2 * r + 1]));
        asm("v_cvt_pk_bf16_f32 %0, %1, %2" : "=v"(u3) : "v"(sB1[2 * r]), "v"(sB1[2 * r + 1]));
        sA0[2 * r] = __uint_as_float(u0);
        sA1[2 * r] = __uint_as_float(u1);
        sB0[2 * r] = __uint_as_float(u2);
        sB1[2 * r] = __uint_as_float(u3);
    }
    __builtin_amdgcn_s_setprio(1);
#pragma unroll
    for (int kc = 0; kc < 4; kc++) {
        const int bs = (kc & 1) * 8;
        bf16x8 pfA, pfB;
        {
            float e0 = (kc < 2) ? sA0[bs + 0] : sA1[bs + 0];
            float e4 = (kc < 2) ? sA0[bs + 4] : sA1[bs + 4];
            float e2 = (kc < 2) ? sA0[bs + 2] : sA1[bs + 2];
            float e6 = (kc < 2) ? sA0[bs + 6] : sA1[bs + 6];
            auto uA = __builtin_amdgcn_permlane32_swap(__float_as_uint(e0), __float_as_uint(e4), false, false);
            auto uB = __builtin_amdgcn_permlane32_swap(__float_as_uint(e2), __float_as_uint(e6), false, false);
            u32x4 t; t.x = uA[0]; t.y = uB[0]; t.z = uA[1]; t.w = uB[1];
            pfA = __builtin_bit_cast(bf16x8, t);
        }
        {
            float e0 = (kc < 2) ? sB0[bs + 0] : sB1[bs + 0];
            float e4 = (kc < 2) ? sB0[bs + 4] : sB1[bs + 4];
            float e2 = (kc < 2) ? sB0[bs + 2] : sB1[bs + 2];
            float e6 = (kc < 2) ? sB0[bs + 6] : sB1[bs + 6];
            auto uA = __builtin_amdgcn_permlane32_swap(__float_as_uint(e0), __float_as_uint(e4), false, false);
            auto uB = __builtin_amdgcn_permlane32_swap(__float_as_uint(e2), __float_as_uint(e6), false, false);
            u32x4 t; t.x = uA[0]; t.y = uB[0]; t.z = uA[1]; t.w = uB[1];
            pfB = __builtin_bit_cast(bf16x8, t);
        }
        bf16x8 va  = *(const bf16x8*)(LB + 8192 + BUF * 4096 + l31 * 64 + so[kc]);
        bf16x8 vb2 = *(const bf16x8*)(LB + 8192 + BUF * 4096 + (32 + l31) * 64 + so[kc]);
        OA0 = __builtin_amdgcn_mfma_f32_32x32x16_bf16(va,  pfA, OA0, 0, 0, 0);
        OA1 = __builtin_amdgcn_mfma_f32_32x32x16_bf16(vb2, pfA, OA1, 0, 0, 0);
        OB0 = __builtin_amdgcn_mfma_f32_32x32x16_bf16(va,  pfB, OB0, 0, 0, 0);
        OB1 = __builtin_amdgcn_mfma_f32_32x32x16_bf16(vb2, pfB, OB1, 0, 0, 0);
        SsA = __builtin_amdgcn_mfma_f32_32x32x16_bf16(ones, pfA, SsA, 0, 0, 0);
        SsB = __builtin_amdgcn_mfma_f32_32x32x16_bf16(ones, pfB, SsB, 0, 0, 0);
    }
    __builtin_amdgcn_s_setprio(0);
    // write-after-read fence: all waves done reading buf before next iter overwrites it
    __builtin_amdgcn_sched_barrier(0);
    __builtin_amdgcn_s_barrier();
}

__global__ __launch_bounds__(256, 2) void attn_mfma_kernel(const unsigned short* __restrict__ qbp,
                                                           const unsigned short* __restrict__ kbp,
                                                           const unsigned short* __restrict__ vtp,
                                                           unsigned short* __restrict__ aout) {
    __shared__ unsigned short LB[4 * 4096];      // K0,K1,V0,V1
    const int tid = threadIdx.x;
    const int wv = tid >> 6;       // 0..3
    const int l = tid & 63;
    const int l31 = l & 31, hi = l >> 5;

    const int wg = blockIdx.x;                    // 0..511
    const int Lidx = (wg & 7) * 64 + (wg >> 3);
    const int bh = Lidx >> 3;
    const int q0 = (Lidx & 7) * 256;

    const unsigned short* qp = qbp + (size_t)bh * (NN * HD);
    const unsigned short* kp = kbp + (size_t)bh * (NN * HD);
    const unsigned short* vp = vtp + (size_t)bh * (NN * HD);

    const int r0 = (wv * 2 + 0) * 8 + (l >> 3);
    const int r1 = (wv * 2 + 1) * 8 + (l >> 3);
    const int c0 = ((l & 7) ^ (r0 & 7)) * 8;
    const int c1 = ((l & 7) ^ (r1 & 7)) * 8;
    const unsigned short* kn0 = kp + r0 * HD + c0;
    const unsigned short* kn1 = kp + r1 * HD + c1;
    const unsigned short* vn0 = vp + (size_t)r0 * NN + c0;
    const unsigned short* vn1 = vp + (size_t)r1 * NN + c1;

    __builtin_amdgcn_global_load_lds((AS1 void*)kn0, (AS3 void*)(&LB[(wv * 2 + 0) * 512]), 16, 0, 0);
    __builtin_amdgcn_global_load_lds((AS1 void*)kn1, (AS3 void*)(&LB[(wv * 2 + 1) * 512]), 16, 0, 0);
    __builtin_amdgcn_global_load_lds((AS1 void*)vn0, (AS3 void*)(&LB[8192 + (wv * 2 + 0) * 512]), 16, 0, 0);
    __builtin_amdgcn_global_load_lds((AS1 void*)vn1, (AS3 void*)(&LB[8192 + (wv * 2 + 1) * 512]), 16, 0, 0);
    kn0 += 4096; kn1 += 4096; vn0 += 64; vn1 += 64;

    const unsigned short* qr = qp + (size_t)(q0 + wv * 64 + l31) * HD;
    bf16x8 qfA[4], qfB[4];
#pragma unroll
    for (int dc = 0; dc < 4; dc++) {
        qfA[dc] = *(const bf16x8*)(qr + dc * 16 + hi * 8);
        qfB[dc] = *(const bf16x8*)(qr + 32 * HD + dc * 16 + hi * 8);
    }

    int so[4];
#pragma unroll
    for (int i = 0; i < 4; i++) so[i] = ((2 * i + hi) ^ (l31 & 7)) * 8;

    f32x16 Z;
#pragma unroll
    for (int r = 0; r < 16; r++) Z[r] = 0.0f;
    f32x16 OA0 = Z, OA1 = Z, OB0 = Z, OB1 = Z, SsA = Z, SsB = Z;
    bf16x8 ones;
#pragma unroll
    for (int j = 0; j < 8; j++) ones[j] = (short)0x3F80;  // bf16 1.0

    __syncthreads();

    for (int ktb = 0; ktb < NT; ktb += 2) {
        attn_iter<0>(LB, wv, l31, kn0, kn1, vn0, vn1, so, qfA, qfB,
                     Z, ones, OA0, OA1, OB0, OB1, SsA, SsB);
        attn_iter<1>(LB, wv, l31, kn0, kn1, vn0, vn1, so, qfA, qfB,
                     Z, ones, OA0, OA1, OB0, OB1, SsA, SsB);
    }

    const int b_ = bh >> 4, hh = bh & 15;
    const float invA = 1.0f / SsA[0], invB = 1.0f / SsB[0];
    const size_t mrowA = (size_t)(b_ * NN + q0 + wv * 64 + l31) * CC + hh * HD;
    const size_t mrowB = mrowA + (size_t)32 * CC;
#pragma unroll
    for (int rq = 0; rq < 4; rq++) {
        u16x4 a0, a1, b0, b1;
#pragma unroll
        for (int j = 0; j < 4; j++) {
            a0[j] = f2bf(OA0[rq * 4 + j] * invA);
            a1[j] = f2bf(OA1[rq * 4 + j] * invA);
            b0[j] = f2bf(OB0[rq * 4 + j] * invB);
            b1[j] = f2bf(OB1[rq * 4 + j] * invB);
        }
        *(u16x4*)(aout + mrowA + rq * 8 + hi * 4) = a0;
        *(u16x4*)(aout + mrowA + 32 + rq * 8 + hi * 4) = a1;
        *(u16x4*)(aout + mrowB + rq * 8 + hi * 4) = b0;
        *(u16x4*)(aout + mrowB + 32 + rq * 8 + hi * 4) = b1;
    }
}

// ---------------- kernel 6: proj GEMM, dbuf + counted vmcnt pipeline + bias ----------------
__global__ __launch_bounds__(256) void proj_gemm_kernel(const unsigned short* __restrict__ A,
                                                        const unsigned short* __restrict__ Bw,
                                                        const float* __restrict__ bp,
                                                        float* __restrict__ out) {
    __shared__ unsigned short Asl[2][128 * 64];
    __shared__ unsigned short Bsl[2][128 * 64];
    const int tid = threadIdx.x;
    const int wv = tid >> 6, l = tid & 63;
    const int wm = wv >> 1, wn = wv & 1;
    const int lg = l >> 4, l15 = l & 15;
    const int m0 = blockIdx.x * 128, n0 = blockIdx.y * 128;

    const unsigned short* asrc[4];
    const unsigned short* bsrc[4];
#pragma unroll
    for (int i = 0; i < 4; i++) {
        int c = (wv * 4 + i) * 64 + l;
        int r = c >> 3, kc = c & 7;
        int sc = (kc ^ (r & 7)) * 8;
        asrc[i] = A + (size_t)(m0 + r) * CC + sc;
        bsrc[i] = Bw + (size_t)(n0 + r) * CC + sc;
    }

    f32x4 acc[4][4];
#pragma unroll
    for (int i = 0; i < 4; i++)
#pragma unroll
        for (int j = 0; j < 4; j++) acc[i][j] = f32x4{0.f, 0.f, 0.f, 0.f};

    GSTAGE(Asl, Bsl, 0);
    for (int ktb = 0; ktb < 16; ktb += 2) {
        GSTAGE(Asl, Bsl, 1);
        GSYNC_PRE();
        GCOMPUTE(Asl, Bsl, 0);
        GSYNC_POST();
        GSTAGE(Asl, Bsl, 0);     // tail iteration stages a harmless dummy
        GSYNC_PRE();
        GCOMPUTE(Asl, Bsl, 1);
        GSYNC_POST();
    }

    float bias[4];
#pragma unroll
    for (int nj = 0; nj < 4; nj++) bias[nj] = bp[n0 + wn * 64 + nj * 16 + l15];
#pragma unroll
    for (int mi = 0; mi < 4; mi++)
#pragma unroll
        for (int nj = 0; nj < 4; nj++) {
            int oc = n0 + wn * 64 + nj * 16 + l15;
#pragma unroll
            for (int reg = 0; reg < 4; reg++) {
                int m = m0 + wm * 64 + mi * 16 + lg * 4 + reg;
                out[(size_t)m * CC + oc] = acc[mi][nj][reg] + bias[nj];
            }
        }
}

extern "C" void kernel_launch(void* const* d_in, const int* in_sizes, int n_in,
                              void* d_out, int out_size, void* d_ws, size_t ws_size,
                              hipStream_t stream) {
    const float* x      = (const float*)d_in[0];
    const float* t_x    = (const float*)d_in[1];
    const float* t_y    = (const float*)d_in[2];
    const float* t_z    = (const float*)d_in[3];
    const float* w_qkv  = (const float*)d_in[4];
    const float* w_proj = (const float*)d_in[5];
    const float* b_proj = (const float*)d_in[6];
    const float* freqs  = (const float*)d_in[7];
    float* out = (float*)d_out;

    unsigned short* xb     = (unsigned short*)d_ws;            // MM*CC
    unsigned short* wqkvb  = xb + (size_t)MM * CC;             // K3*CC
    unsigned short* wprojb = wqkvb + (size_t)K3 * CC;          // CC*CC
    unsigned short* qbuf   = wprojb + (size_t)CC * CC;         // B*H*N*HD
    unsigned short* kbuf   = qbuf + (size_t)BB * HH * NN * HD;
    unsigned short* vbT    = kbuf + (size_t)BB * HH * NN * HD; // [bh][d][n]
    unsigned short* attnb  = vbT + (size_t)BB * HH * NN * HD;
    float* csT   = (float*)(attnb + (size_t)MM * CC);          // NN*NF float2
    float* tnorm = csT + (size_t)2 * NN * NF;

    tnorm_kernel<<<3, 256, 0, stream>>>(t_x, t_y, t_z, tnorm);
    angle_kernel<<<NN, 512, 0, stream>>>(freqs, tnorm, csT);
    cvt_all_kernel<<<XBLK + WQBLK + WPBLK, 256, 0, stream>>>(x, w_qkv, w_proj,
                                                             xb, wqkvb, wprojb);
    qkv_gemm_kernel<<<dim3(MM / 128, K3 / 128), 256, 0, stream>>>(xb, wqkvb, csT,
                                                                  qbuf, kbuf, vbT);
    attn_mfma_kernel<<<512, 256, 0, stream>>>(qbuf, kbuf, vbT, attnb);
    proj_gemm_kernel<<<dim3(MM / 128, CC / 128), 256, 0, stream>>>(attnb, wprojb, b_proj, out);
}